// Round 1
// baseline (112144.543 us; speedup 1.0000x reference)
//
#include <hip/hip_runtime.h>
#include <stdint.h>

typedef unsigned short u16;
typedef _Float16 h2f16 __attribute__((ext_vector_type(2)));

#define BB    16
#define TENC  256
#define TDEC  200
#define NMELS 80
#define EDIM  512
#define PREN  256
#define ARN   1024
#define ATTN  128
#define NFILT 32
#define KSIZE 31

#define NBLK  256
#define NTHR  1024

// ---- ws layout (floats); max used offset 1,351,696 f = 5.41 MB (< proven 7.44 MB) ----
#define OFF_AW     0          // 4096
#define OFF_AWC    4096       // 4096
#define OFF_AC     8192       // 16384
#define OFF_DC     24576      // 16384
#define OFF_XCAT1  49152      // [pre(256)|ctx(512)|ah(1024)] rows x16b = 28672 f
#define OFF_XCAT2  77824      // [ah(1024)|ctx(512)|dh(1024)] rows x16b = 40960 f
#define STATE_F    118784
#define OFF_PRETU  118784     // u16[819200]  pre bf16 [t][j*16+b]
#define OFF_PMU    528384     // u16[524288]  pm bf16 [b][j][tt]
#define OFF_Z      790528     // f32 8*16*4096 = 524288  split-K partials (z1 then z2)
#define OFF_PQP    1314816    // f32 16*16*128 = 32768   pq partials [b][ug][j]
#define OFF_EBUF   1347584    // f32 16*256 = 4096       pre-softmax energies
#define OFF_BAR    1351680    // uint barrier counter

__host__ __device__ inline void tf2x32(uint32_t k0, uint32_t k1, uint32_t x0, uint32_t x1,
                                       uint32_t &y0, uint32_t &y1) {
  uint32_t ks2 = k0 ^ k1 ^ 0x1BD11BDAu;
  x0 += k0; x1 += k1;
  const int R0[4] = {13, 15, 26, 6};
  const int R1[4] = {17, 29, 16, 24};
#pragma unroll
  for (int g = 0; g < 5; ++g) {
    const int *R = (g & 1) ? R1 : R0;
#pragma unroll
    for (int i = 0; i < 4; ++i) {
      x0 += x1;
      x1 = (x1 << R[i]) | (x1 >> (32 - R[i]));
      x1 ^= x0;
    }
    switch (g) {
      case 0: x0 += k1;  x1 += ks2 + 1u; break;
      case 1: x0 += ks2; x1 += k0 + 2u;  break;
      case 2: x0 += k0;  x1 += k1 + 3u;  break;
      case 3: x0 += k1;  x1 += ks2 + 4u; break;
      case 4: x0 += ks2; x1 += k0 + 5u;  break;
    }
  }
  y0 = x0; y1 = x1;
}

__device__ inline bool keep_mask(uint32_t k0, uint32_t k1, uint32_t idx) {
  uint32_t y0, y1;
  tf2x32(k0, k1, 0u, idx, y0, y1);
  return (((y0 ^ y1) >> 31) == 0u);
}

__device__ inline float bf2f(u16 v) {
  union { uint32_t u; float f; } x;
  x.u = ((uint32_t)v) << 16;
  return x.f;
}
__device__ inline u16 f2bf(float f) {
  union { float f; uint32_t u; } x;
  x.f = f;
  uint32_t r = ((x.u >> 16) & 1u) + 0x7FFFu;
  return (u16)((x.u + r) >> 16);
}
__device__ inline float sigm(float x) { return 1.f / (1.f + __expf(-x)); }
__device__ inline float ftanh(float x) {
  x = fminf(fmaxf(x, -15.f), 15.f);
  float e = __expf(2.f * x);
  return (e - 1.f) / (e + 1.f);
}

__device__ inline uint32_t packh2(float a, float b) {
  h2f16 h; h[0] = (_Float16)a; h[1] = (_Float16)b;
  union { h2f16 h; uint32_t u; } x; x.h = h; return x.u;
}
__device__ inline h2f16 u2h2(uint32_t u) {
  union { uint32_t u; h2f16 h; } x; x.u = u; return x.h;
}
__device__ inline float fdot2(h2f16 a, h2f16 b, float c) {
#if __has_builtin(__builtin_amdgcn_fdot2)
  return __builtin_amdgcn_fdot2(a, b, c, false);
#else
  return (float)a[0] * (float)b[0] + (float)a[1] * (float)b[1] + c;
#endif
}

// monotonic global barrier (cumulative counter, agent scope)
__device__ inline void gsync(unsigned int *bar, unsigned int target) {
  __syncthreads();
  if (threadIdx.x == 0) {
    __threadfence();
    __hip_atomic_fetch_add(bar, 1u, __ATOMIC_ACQ_REL, __HIP_MEMORY_SCOPE_AGENT);
    while (__hip_atomic_load(bar, __ATOMIC_ACQUIRE, __HIP_MEMORY_SCOPE_AGENT) < target)
      __builtin_amdgcn_s_sleep(2);
  }
  __syncthreads();
}

// ---------------- setup kernels (one-time, unchanged semantics) ----------------
__global__ __launch_bounds__(256) void k_prenet1(const float *__restrict__ dec_in,
                                                 const float *__restrict__ W1,
                                                 u16 *__restrict__ x1,
                                                 uint32_t k0, uint32_t k1) {
  int bid = blockIdx.x;
  int t = bid >> 4, b = bid & 15;
  int tid = threadIdx.x;
  __shared__ float di[NMELS];
  if (tid < NMELS)
    di[tid] = (t == 0) ? 0.f : dec_in[((size_t)b * NMELS + tid) * TDEC + (t - 1)];
  __syncthreads();
  int j = tid;
  float acc = 0.f;
#pragma unroll 4
  for (int m = 0; m < NMELS; ++m) acc += di[m] * W1[(size_t)m * PREN + j];
  acc = fmaxf(acc, 0.f);
  uint32_t idx = ((uint32_t)(t * BB + b)) * PREN + (uint32_t)j;
  acc = keep_mask(k0, k1, idx) ? acc * 2.f : 0.f;
  x1[(t * BB + b) * PREN + j] = f2bf(acc);
}

__global__ __launch_bounds__(256) void k_prenet2(const u16 *__restrict__ x1,
                                                 const float *__restrict__ W2,
                                                 u16 *__restrict__ preTu,
                                                 float *__restrict__ xpre0,
                                                 uint32_t k0, uint32_t k1) {
  int bid = blockIdx.x;
  int t = bid >> 4, b = bid & 15;
  int tid = threadIdx.x;
  __shared__ float xl[PREN];
  xl[tid] = bf2f(x1[(t * BB + b) * PREN + tid]);
  __syncthreads();
  int j = tid;
  float acc = 0.f;
#pragma unroll 4
  for (int k = 0; k < PREN; ++k) acc += xl[k] * W2[(size_t)k * PREN + j];
  acc = fmaxf(acc, 0.f);
  uint32_t idx = ((uint32_t)(t * BB + b)) * PREN + (uint32_t)j;
  acc = keep_mask(k0, k1, idx) ? acc * 2.f : 0.f;
  preTu[(size_t)t * 4096 + j * 16 + b] = f2bf(acc);
  if (t == 0) xpre0[j * 16 + b] = acc;
}

__global__ __launch_bounds__(256) void k_pm(const float *__restrict__ memory,
                                            const float *__restrict__ Wmem,
                                            u16 *__restrict__ pmu) {
  int p = blockIdx.x;          // 64 blocks
  int b = p & 15, jt = p >> 4;
  int tt = threadIdx.x;
  float acc[32];
#pragma unroll
  for (int j = 0; j < 32; ++j) acc[j] = 0.f;
  const float *mrow = memory + ((size_t)b * TENC + tt) * EDIM;
  const float *wb = Wmem + jt * 32;
  for (int e = 0; e < EDIM; ++e) {
    float mv = mrow[e];
    const float *wr = wb + (size_t)e * ATTN;
#pragma unroll
    for (int j = 0; j < 32; ++j) acc[j] += mv * wr[j];
  }
#pragma unroll
  for (int j = 0; j < 32; ++j)
    pmu[((size_t)(b * ATTN + jt * 32 + j)) * TENC + tt] = f2bf(acc[j]);
}

// ---------------- persistent cooperative decoder kernel ----------------
struct F2 { float x, y; };

union Scr {
  uint32_t xs1[112 * 16];                         // z1 x-stage, fp16 pairs [k2][16b]
  uint32_t xs2[160 * 16];                         // z2 x-stage
  struct { F2 part[16 * 64]; float hn[64]; } al;  // aLSTM reduce
  struct {
    float aw_l[96], awc_l[96];
    float lc[64 * 33];
    float pq[128];
    float ep[64 * 17];
  } att;                                          // attention energies (per 64-tt slab)
  struct { float e_l[256]; float red[32]; float smax, sinv; float part[32 * 33]; } ctc;
  struct { float xl[1536]; float part[12 * 81]; } out;
};

struct KArgs {
  const float *memory; const int *mlen;
  const float *aWih, *aWhh, *ab;
  const float *Wq, *vw, *convW, *ldW;
  const float *dWih, *dWhh, *db;
  const float *projW, *projB, *gateW, *gateB;
  const u16 *preTu, *pmu;
  float *aw, *awc, *ac, *dc, *xcat1, *xcat2, *z, *pqp, *ebuf;
  unsigned int *bar;
  float *mel, *gate, *algn;
};

// grid = 256 blocks (1/CU) x 1024 thr. LDS: w1h 57,344 + w2h 81,920 + Scr 14,080 = 153,344 B.
__global__ __launch_bounds__(NTHR) void k_persist(KArgs A) {
  __shared__ uint32_t w1h[112 * 128];   // z1 weight slice, fp16 k-pairs [k2][128cols]
  __shared__ uint32_t w2h[160 * 128];   // z2 weight slice
  __shared__ Scr s;
  const int cb = blockIdx.x;
  const int tid = threadIdx.x;
  const int q = cb >> 5;                // k-chunk 0..7  (z1: 224 rows, z2: 320 rows)
  const int c = cb & 31;                // col-block 0..31 (128 cols of 4096)

  // ---- one-time: stage fp16 weight slices into LDS (read HBM once, not 200x) ----
  for (int i = tid; i < 112 * 128; i += NTHR) {
    int k2 = i >> 7, col = i & 127, cg = c * 128 + col;
    int r0 = q * 224 + k2 * 2;
    float f0 = (r0 < 768) ? A.aWih[(size_t)r0 * 4096 + cg]
                          : A.aWhh[(size_t)(r0 - 768) * 4096 + cg];
    float f1 = (r0 + 1 < 768) ? A.aWih[(size_t)(r0 + 1) * 4096 + cg]
                              : A.aWhh[(size_t)(r0 - 767) * 4096 + cg];
    w1h[i] = packh2(f0, f1);
  }
  for (int i = tid; i < 160 * 128; i += NTHR) {
    int k2 = i >> 7, col = i & 127, cg = c * 128 + col;
    int r0 = q * 320 + k2 * 2;
    float f0 = (r0 < 1536) ? A.dWih[(size_t)r0 * 4096 + cg]
                           : A.dWhh[(size_t)(r0 - 1536) * 4096 + cg];
    float f1 = (r0 + 1 < 1536) ? A.dWih[(size_t)(r0 + 1) * 4096 + cg]
                               : A.dWhh[(size_t)(r0 - 1535) * 4096 + cg];
    w2h[i] = packh2(f0, f1);
  }
  __syncthreads();

  unsigned int tgt = 0;
  for (int t = 0; t < TDEC; ++t) {
    // ================= phase Z1: z1 partials (all 256 blocks) =================
    for (int i = tid; i < 112 * 16; i += NTHR) {
      int k2 = i >> 4, b = i & 15;
      const float *xr = A.xcat1 + (size_t)(q * 224 + k2 * 2) * 16 + b;
      s.xs1[i] = packh2(xr[0], xr[16]);
    }
    __syncthreads();
    {
      int col = tid & 127, bg = tid >> 7;         // 128 cols x 8 groups of 2 batches
      float a0 = 0.f, a1 = 0.f;
      const uint32_t *wp = w1h + col;
      const uint32_t *xp = s.xs1 + bg * 2;
#pragma unroll 8
      for (int k2 = 0; k2 < 112; ++k2) {
        h2f16 w = u2h2(wp[k2 * 128]);
        a0 = fdot2(w, u2h2(xp[k2 * 16]), a0);
        a1 = fdot2(w, u2h2(xp[k2 * 16 + 1]), a1);
      }
      int cg = c * 128 + col;
      A.z[((size_t)q * 16 + bg * 2    ) * 4096 + cg] = a0;
      A.z[((size_t)q * 16 + bg * 2 + 1) * 4096 + cg] = a1;
    }
    gsync(A.bar, tgt += NBLK);

    // ================= phase A-LSTM + pq partials (all 256 blocks) =================
    {
      int b = cb & 15, ug = cb >> 4;              // 16 batches x 16 u-groups of 64
      {
        int u_l = tid & 63, j = tid >> 6;         // j: kc(8) x gate-half(2)
        int kc = j & 7, gh = j >> 3;
        const float *zb = A.z + ((size_t)(kc * 16 + b)) * 4096 + gh * 2048 + (ug * 64 + u_l);
        F2 p; p.x = zb[0]; p.y = zb[1024];
        s.al.part[j * 64 + u_l] = p;
      }
      __syncthreads();
      if (tid < 64) {
        int uu = ug * 64 + tid;
        float g0 = 0.f, g1 = 0.f, g2 = 0.f, g3 = 0.f;
#pragma unroll
        for (int kc = 0; kc < 8; ++kc) {
          F2 v0 = s.al.part[kc * 64 + tid];
          F2 v1 = s.al.part[(8 + kc) * 64 + tid];
          g0 += v0.x; g1 += v0.y; g2 += v1.x; g3 += v1.y;
        }
        float zi = g0 + A.ab[uu], zf = g1 + A.ab[1024 + uu];
        float zg = g2 + A.ab[2048 + uu], zo = g3 + A.ab[3072 + uu];
        float cn = sigm(zf) * A.ac[b * 1024 + uu] + sigm(zi) * ftanh(zg);
        float hn = sigm(zo) * ftanh(cn);
        A.ac[b * 1024 + uu] = cn;
        A.xcat1[(size_t)(768 + uu) * 16 + b] = hn;
        A.xcat2[(size_t)uu * 16 + b] = hn;
        s.al.hn[tid] = hn;
      }
      __syncthreads();
      if (tid < 128) {
        float a = 0.f;
        const float *wq = A.Wq + (size_t)(ug * 64) * 128 + tid;
#pragma unroll 4
        for (int k = 0; k < 64; ++k) a += s.al.hn[k] * wq[(size_t)k * 128];
        A.pqp[(size_t)(b * 16 + ug) * 128 + tid] = a;
      }
    }
    gsync(A.bar, tgt += NBLK);

    // ================= phase ATT-A: conv + energies (64 blocks: 16b x 4 tt-slabs) ====
    if (cb < 64) {
      int b = cb & 15, tq = cb >> 4;
      if (tid < 96) {
        int gi = tq * 64 - 16 + tid;
        bool ok = (gi >= 0 && gi < 256);
        s.att.aw_l[tid]  = ok ? A.aw[b * 256 + gi]  : 0.f;
        s.att.awc_l[tid] = ok ? A.awc[b * 256 + gi] : 0.f;
      }
      if (tid >= 128 && tid < 256) {
        int j = tid - 128;
        float sum = 0.f;
#pragma unroll
        for (int g = 0; g < 16; ++g) sum += A.pqp[(size_t)(b * 16 + g) * 128 + j];
        s.att.pq[j] = sum;
      }
      __syncthreads();
      {  // conv: 64 tt x 16 groups of 2 filters
        int tt_l = tid & 63, fg = tid >> 6;
        int f0 = fg * 2;
        float a0 = 0.f, a1 = 0.f;
        for (int k = 0; k < KSIZE; ++k) {
          float av = s.att.aw_l[tt_l + k + 1];
          float cv = s.att.awc_l[tt_l + k + 1];
          a0 += av * A.convW[f0 * 62 + k]       + cv * A.convW[f0 * 62 + 31 + k];
          a1 += av * A.convW[(f0 + 1) * 62 + k] + cv * A.convW[(f0 + 1) * 62 + 31 + k];
        }
        s.att.lc[tt_l * 33 + f0]     = a0;
        s.att.lc[tt_l * 33 + f0 + 1] = a1;
      }
      __syncthreads();
      {  // energies: 64 tt x 16 groups of 8 j
        int tt_l = tid & 63, g = tid >> 6;
        int tt = tq * 64 + tt_l, j0 = g * 8;
        float acc[8] = {0, 0, 0, 0, 0, 0, 0, 0};
        for (int f = 0; f < NFILT; ++f) {
          float lv = s.att.lc[tt_l * 33 + f];
          const float *lw = A.ldW + f * ATTN + j0;
#pragma unroll
          for (int jj = 0; jj < 8; ++jj) acc[jj] += lv * lw[jj];
        }
        float es = 0.f;
#pragma unroll
        for (int jj = 0; jj < 8; ++jj) {
          float sv = acc[jj] + s.att.pq[j0 + jj]
                   + bf2f(A.pmu[((size_t)(b * 128 + j0 + jj)) * 256 + tt]);
          es += ftanh(sv) * A.vw[j0 + jj];
        }
        s.att.ep[tt_l * 17 + g] = es;
      }
      __syncthreads();
      if (tid < 64) {
        float e = 0.f;
#pragma unroll
        for (int g = 0; g < 16; ++g) e += s.att.ep[tid * 17 + g];
        int tt = tq * 64 + tid;
        if (tt >= A.mlen[b]) e = -1e9f;
        A.ebuf[b * 256 + tt] = e;
      }
    }
    gsync(A.bar, tgt += NBLK);

    // ===== phase ATT-C: softmax (replicated) + ctx (256 blocks: 16b x 16 e-chunks) ====
    {
      int b = cb & 15, ec = cb >> 4;
      if (tid < 256) s.ctc.e_l[tid] = A.ebuf[b * 256 + tid];
      __syncthreads();
      if (tid < 32) {
        float m = -1e30f;
#pragma unroll
        for (int i = 0; i < 8; ++i) m = fmaxf(m, s.ctc.e_l[tid * 8 + i]);
        s.ctc.red[tid] = m;
      }
      __syncthreads();
      if (tid == 0) {
        float m = -1e30f;
        for (int i = 0; i < 32; ++i) m = fmaxf(m, s.ctc.red[i]);
        s.ctc.smax = m;
      }
      __syncthreads();
      if (tid < 256) s.ctc.e_l[tid] = __expf(s.ctc.e_l[tid] - s.ctc.smax);
      __syncthreads();
      if (tid < 32) {
        float sm = 0.f;
#pragma unroll
        for (int i = 0; i < 8; ++i) sm += s.ctc.e_l[tid * 8 + i];
        s.ctc.red[tid] = sm;
      }
      __syncthreads();
      if (tid == 0) {
        float sm = 0.f;
        for (int i = 0; i < 32; ++i) sm += s.ctc.red[i];
        s.ctc.sinv = 1.f / sm;
      }
      __syncthreads();
      if (tid < 256) s.ctc.e_l[tid] *= s.ctc.sinv;    // e_l is now w
      __syncthreads();
      if (ec == 0 && tid < 256) {                     // one chunk-block owns state writes
        float w = s.ctc.e_l[tid];
        A.aw[b * 256 + tid] = w;
        A.awc[b * 256 + tid] += w;
        A.algn[((size_t)b * TDEC + t) * TENC + tid] = w;
      }
      {
        int e_l = tid & 31, sub = tid >> 5;           // 32 e x 32 tt-subsets of 8
        const float *mp = A.memory + ((size_t)(b * 256) + sub * 8) * 512 + ec * 32 + e_l;
        float a = 0.f;
#pragma unroll
        for (int i = 0; i < 8; ++i) a += s.ctc.e_l[sub * 8 + i] * mp[(size_t)i * 512];
        s.ctc.part[e_l * 33 + sub] = a;
      }
      __syncthreads();
      if (tid < 32) {
        float sum = 0.f;
#pragma unroll
        for (int i = 0; i < 32; ++i) sum += s.ctc.part[tid * 33 + i];
        int eg = ec * 32 + tid;
        A.xcat1[(size_t)(256 + eg) * 16 + b] = sum;
        A.xcat2[(size_t)(1024 + eg) * 16 + b] = sum;
      }
    }
    gsync(A.bar, tgt += NBLK);

    // ================= phase Z2: z2 partials (all 256 blocks) =================
    for (int i = tid; i < 160 * 16; i += NTHR) {
      int k2 = i >> 4, b = i & 15;
      const float *xr = A.xcat2 + (size_t)(q * 320 + k2 * 2) * 16 + b;
      s.xs2[i] = packh2(xr[0], xr[16]);
    }
    __syncthreads();
    {
      int col = tid & 127, bg = tid >> 7;
      float a0 = 0.f, a1 = 0.f;
      const uint32_t *wp = w2h + col;
      const uint32_t *xp = s.xs2 + bg * 2;
#pragma unroll 8
      for (int k2 = 0; k2 < 160; ++k2) {
        h2f16 w = u2h2(wp[k2 * 128]);
        a0 = fdot2(w, u2h2(xp[k2 * 16]), a0);
        a1 = fdot2(w, u2h2(xp[k2 * 16 + 1]), a1);
      }
      int cg = c * 128 + col;
      A.z[((size_t)q * 16 + bg * 2    ) * 4096 + cg] = a0;
      A.z[((size_t)q * 16 + bg * 2 + 1) * 4096 + cg] = a1;
    }
    gsync(A.bar, tgt += NBLK);

    // ============ phase OUT: dLSTM + projection (16 blocks) + pre prefetch (4) =======
    if (cb < 16) {
      int b = cb;
      {
        int u = tid;
        float zi = 0.f, zf = 0.f, zg = 0.f, zo = 0.f;
        for (int kc = 0; kc < 8; ++kc) {
          const float *zb = A.z + ((size_t)(kc * 16 + b)) * 4096;
          zi += zb[u]; zf += zb[u + 1024]; zg += zb[u + 2048]; zo += zb[u + 3072];
        }
        zi += A.db[u]; zf += A.db[u + 1024]; zg += A.db[u + 2048]; zo += A.db[u + 3072];
        float cn = sigm(zf) * A.dc[b * 1024 + u] + sigm(zi) * ftanh(zg);
        float hn = sigm(zo) * ftanh(cn);
        A.dc[b * 1024 + u] = cn;
        A.xcat2[(size_t)(1536 + u) * 16 + b] = hn;
        s.out.xl[u] = hn;
      }
      if (tid < 512) s.out.xl[1024 + tid] = A.xcat2[(size_t)(1024 + tid) * 16 + b];
      __syncthreads();
      if (tid < 960) {
        int col = tid % 80, kc = tid / 80;          // 12 k-groups x 128
        const float *wp = A.projW + (size_t)(kc * 128) * 80 + col;
        const float *xk = s.out.xl + kc * 128;
        float a = 0.f;
#pragma unroll 4
        for (int kk = 0; kk < 128; ++kk) a += xk[kk] * wp[(size_t)kk * 80];
        s.out.part[kc * 81 + col] = a;
      } else if (tid < 972) {
        int kc = tid - 960;
        const float *xk = s.out.xl + kc * 128;
        const float *gk = A.gateW + kc * 128;
        float a = 0.f;
#pragma unroll 4
        for (int kk = 0; kk < 128; ++kk) a += xk[kk] * gk[kk];
        s.out.part[kc * 81 + 80] = a;
      }
      __syncthreads();
      if (tid < 81) {
        float sum = 0.f;
#pragma unroll
        for (int kc = 0; kc < 12; ++kc) sum += s.out.part[kc * 81 + tid];
        if (tid < 80) A.mel[((size_t)b * 80 + tid) * TDEC + t] = sum + A.projB[tid];
        else          A.gate[(size_t)b * TDEC + t] = sum + A.gateB[0];
      }
    } else if (cb < 20) {
      if (t + 1 < TDEC) {
        int idx = (cb - 16) * 1024 + tid;
        A.xcat1[idx] = bf2f(A.preTu[(size_t)(t + 1) * 4096 + idx]);
      }
    }
    gsync(A.bar, tgt += NBLK);
  }
}

extern "C" void kernel_launch(void *const *d_in, const int *in_sizes, int n_in,
                              void *d_out, int out_size, void *d_ws, size_t ws_size,
                              hipStream_t stream) {
  (void)in_sizes; (void)n_in; (void)out_size; (void)ws_size;
  const float *memory = (const float *)d_in[0];
  const float *dec_in = (const float *)d_in[1];
  const int   *mlen   = (const int *)d_in[2];
  const float *pw1    = (const float *)d_in[3];
  const float *pw2    = (const float *)d_in[4];
  const float *aWih   = (const float *)d_in[5];
  const float *aWhh   = (const float *)d_in[6];
  const float *ab     = (const float *)d_in[7];
  const float *wq     = (const float *)d_in[8];
  const float *wmem   = (const float *)d_in[9];
  const float *vw     = (const float *)d_in[10];
  const float *convW  = (const float *)d_in[11];
  const float *ldW    = (const float *)d_in[12];
  const float *dWih   = (const float *)d_in[13];
  const float *dWhh   = (const float *)d_in[14];
  const float *db     = (const float *)d_in[15];
  const float *projW  = (const float *)d_in[16];
  const float *projB  = (const float *)d_in[17];
  const float *gateW  = (const float *)d_in[18];
  const float *gateB  = (const float *)d_in[19];

  float *out_mel  = (float *)d_out;
  float *out_gate = out_mel + (size_t)16 * 80 * 200;
  float *out_algn = out_gate + (size_t)16 * 200;

  float *ws = (float *)d_ws;
  float *aw    = ws + OFF_AW;
  float *awc   = ws + OFF_AWC;
  float *ac    = ws + OFF_AC;
  float *dc    = ws + OFF_DC;
  float *xcat1 = ws + OFF_XCAT1;
  float *xcat2 = ws + OFF_XCAT2;
  float *xpre  = xcat1;
  u16 *preTu = (u16 *)(ws + OFF_PRETU);
  u16 *pmu   = (u16 *)(ws + OFF_PMU);
  float *z    = ws + OFF_Z;
  float *pqp  = ws + OFF_PQP;
  float *ebuf = ws + OFF_EBUF;
  unsigned int *bar = (unsigned int *)(ws + OFF_BAR);
  u16 *x1u   = (u16 *)z;                   // prenet temp alias (pre-loop only)

  hipMemsetAsync(ws, 0, STATE_F * sizeof(float), stream);
  hipMemsetAsync(bar, 0, 16, stream);

  uint32_t K1a, K1b, K2a, K2b;
  tf2x32(0u, 42u, 0u, 0u, K1a, K1b);
  tf2x32(0u, 42u, 0u, 1u, K2a, K2b);

  k_prenet1<<<TDEC * BB, 256, 0, stream>>>(dec_in, pw1, x1u, K1a, K1b);
  k_prenet2<<<TDEC * BB, 256, 0, stream>>>(x1u, pw2, preTu, xpre, K2a, K2b);
  k_pm<<<64, 256, 0, stream>>>(memory, wmem, pmu);

  KArgs ka;
  ka.memory = memory; ka.mlen = mlen;
  ka.aWih = aWih; ka.aWhh = aWhh; ka.ab = ab;
  ka.Wq = wq; ka.vw = vw; ka.convW = convW; ka.ldW = ldW;
  ka.dWih = dWih; ka.dWhh = dWhh; ka.db = db;
  ka.projW = projW; ka.projB = projB; ka.gateW = gateW; ka.gateB = gateB;
  ka.preTu = preTu; ka.pmu = pmu;
  ka.aw = aw; ka.awc = awc; ka.ac = ac; ka.dc = dc;
  ka.xcat1 = xcat1; ka.xcat2 = xcat2; ka.z = z; ka.pqp = pqp; ka.ebuf = ebuf;
  ka.bar = bar;
  ka.mel = out_mel; ka.gate = out_gate; ka.algn = out_algn;

  void *kp[] = { &ka };
  hipLaunchCooperativeKernel((void *)k_persist, dim3(NBLK), dim3(NTHR), kp, 0, stream);
}

// Round 2
// 33923.257 us; speedup vs baseline: 3.3058x; 3.3058x over previous
//
#include <hip/hip_runtime.h>
#include <stdint.h>

typedef unsigned short u16;
typedef _Float16 h2f16 __attribute__((ext_vector_type(2)));

#define BB    16
#define TENC  256
#define TDEC  200
#define NMELS 80
#define EDIM  512
#define PREN  256
#define ARN   1024
#define ATTN  128
#define NFILT 32
#define KSIZE 31

#define NBLK  256
#define NTHR  1024

// ---- ws layout (floats); max used offset ~1,353,728 f = 5.41 MB (< proven 7.44 MB) ----
#define OFF_AW     0          // 4096
#define OFF_AWC    4096       // 4096
#define OFF_AC     8192       // 16384
#define OFF_DC     24576      // 16384
#define OFF_XCAT1  49152      // [pre(256)|ctx(512)|ah(1024)] rows x16b = 28672 f
#define OFF_XCAT2  77824      // [ah(1024)|ctx(512)|dh(1024)] rows x16b = 40960 f
#define STATE_F    118784
#define OFF_PRETU  118784     // u16[819200]  pre bf16 [t][j*16+b]
#define OFF_PMU    528384     // u16[524288]  pm bf16 [b][j][tt]
#define OFF_Z      790528     // f32 8*16*4096 = 524288  split-K partials (z1 then z2)
#define OFF_PQP    1314816    // f32 16*16*128 = 32768   pq partials [b][ug][j]
#define OFF_EBUF   1347584    // f32 16*256 = 4096       pre-softmax energies
#define OFF_BAR    1351680    // uint[2048] hierarchical barrier (8KB)

__host__ __device__ inline void tf2x32(uint32_t k0, uint32_t k1, uint32_t x0, uint32_t x1,
                                       uint32_t &y0, uint32_t &y1) {
  uint32_t ks2 = k0 ^ k1 ^ 0x1BD11BDAu;
  x0 += k0; x1 += k1;
  const int R0[4] = {13, 15, 26, 6};
  const int R1[4] = {17, 29, 16, 24};
#pragma unroll
  for (int g = 0; g < 5; ++g) {
    const int *R = (g & 1) ? R1 : R0;
#pragma unroll
    for (int i = 0; i < 4; ++i) {
      x0 += x1;
      x1 = (x1 << R[i]) | (x1 >> (32 - R[i]));
      x1 ^= x0;
    }
    switch (g) {
      case 0: x0 += k1;  x1 += ks2 + 1u; break;
      case 1: x0 += ks2; x1 += k0 + 2u;  break;
      case 2: x0 += k0;  x1 += k1 + 3u;  break;
      case 3: x0 += k1;  x1 += ks2 + 4u; break;
      case 4: x0 += ks2; x1 += k0 + 5u;  break;
    }
  }
  y0 = x0; y1 = x1;
}

__device__ inline bool keep_mask(uint32_t k0, uint32_t k1, uint32_t idx) {
  uint32_t y0, y1;
  tf2x32(k0, k1, 0u, idx, y0, y1);
  return (((y0 ^ y1) >> 31) == 0u);
}

__device__ inline float bf2f(u16 v) {
  union { uint32_t u; float f; } x;
  x.u = ((uint32_t)v) << 16;
  return x.f;
}
__device__ inline u16 f2bf(float f) {
  union { float f; uint32_t u; } x;
  x.f = f;
  uint32_t r = ((x.u >> 16) & 1u) + 0x7FFFu;
  return (u16)((x.u + r) >> 16);
}
__device__ inline float sigm(float x) { return 1.f / (1.f + __expf(-x)); }
__device__ inline float ftanh(float x) {
  x = fminf(fmaxf(x, -15.f), 15.f);
  float e = __expf(2.f * x);
  return (e - 1.f) / (e + 1.f);
}

__device__ inline uint32_t packh2(float a, float b) {
  h2f16 h; h[0] = (_Float16)a; h[1] = (_Float16)b;
  union { h2f16 h; uint32_t u; } x; x.h = h; return x.u;
}
__device__ inline h2f16 u2h2(uint32_t u) {
  union { uint32_t u; h2f16 h; } x; x.u = u; return x.h;
}
__device__ inline float fdot2(h2f16 a, h2f16 b, float c) {
#if __has_builtin(__builtin_amdgcn_fdot2)
  return __builtin_amdgcn_fdot2(a, b, c, false);
#else
  return (float)a[0] * (float)b[0] + (float)a[1] * (float)b[1] + c;
#endif
}

// ---- hierarchical epoch barrier -------------------------------------------------
// Layout within bar (u32 units, 256B-spaced cachelines):
//   arr[g]  at g*64        (g = cb&7, 32 blocks/group, relaxed adds)
//   gctr    at 512         (8 group-leaders, relaxed adds)
//   rel[g]  at 576 + g*64  (single writer/epoch, 32 relaxed pollers)
// Exactly ONE release fence + ONE acquire fence per block per barrier; all
// counter ops RELAXED (no per-op L2 writeback/invalidate).
__device__ inline void gsync(unsigned int *bar, unsigned int e, int cb) {
  __syncthreads();
  if (threadIdx.x == 0) {
#if __has_builtin(__builtin_amdgcn_fence)
    __builtin_amdgcn_fence(__ATOMIC_RELEASE, "agent");
#else
    __threadfence();
#endif
    int g = cb & 7;
    unsigned int *arr = bar + g * 64;
    unsigned int *gct = bar + 512;
    unsigned int *rel = bar + 576 + g * 64;
    unsigned int old = __hip_atomic_fetch_add(arr, 1u, __ATOMIC_RELAXED,
                                              __HIP_MEMORY_SCOPE_AGENT);
    if (old == e * 32u - 1u) {                 // last arriver of this group
      unsigned int o2 = __hip_atomic_fetch_add(gct, 1u, __ATOMIC_RELAXED,
                                               __HIP_MEMORY_SCOPE_AGENT);
      if (o2 == e * 8u - 1u) {                 // last group globally -> publish
#pragma unroll
        for (int g2 = 0; g2 < 8; ++g2)
          __hip_atomic_store(bar + 576 + g2 * 64, e, __ATOMIC_RELAXED,
                             __HIP_MEMORY_SCOPE_AGENT);
      }
    }
    while (__hip_atomic_load(rel, __ATOMIC_RELAXED, __HIP_MEMORY_SCOPE_AGENT) < e)
      __builtin_amdgcn_s_sleep(8);
#if __has_builtin(__builtin_amdgcn_fence)
    __builtin_amdgcn_fence(__ATOMIC_ACQUIRE, "agent");
#else
    __threadfence();
#endif
  }
  __syncthreads();
}

// ---------------- setup kernels (one-time, unchanged semantics) ----------------
__global__ __launch_bounds__(256) void k_prenet1(const float *__restrict__ dec_in,
                                                 const float *__restrict__ W1,
                                                 u16 *__restrict__ x1,
                                                 uint32_t k0, uint32_t k1) {
  int bid = blockIdx.x;
  int t = bid >> 4, b = bid & 15;
  int tid = threadIdx.x;
  __shared__ float di[NMELS];
  if (tid < NMELS)
    di[tid] = (t == 0) ? 0.f : dec_in[((size_t)b * NMELS + tid) * TDEC + (t - 1)];
  __syncthreads();
  int j = tid;
  float acc = 0.f;
#pragma unroll 4
  for (int m = 0; m < NMELS; ++m) acc += di[m] * W1[(size_t)m * PREN + j];
  acc = fmaxf(acc, 0.f);
  uint32_t idx = ((uint32_t)(t * BB + b)) * PREN + (uint32_t)j;
  acc = keep_mask(k0, k1, idx) ? acc * 2.f : 0.f;
  x1[(t * BB + b) * PREN + j] = f2bf(acc);
}

__global__ __launch_bounds__(256) void k_prenet2(const u16 *__restrict__ x1,
                                                 const float *__restrict__ W2,
                                                 u16 *__restrict__ preTu,
                                                 float *__restrict__ xpre0,
                                                 uint32_t k0, uint32_t k1) {
  int bid = blockIdx.x;
  int t = bid >> 4, b = bid & 15;
  int tid = threadIdx.x;
  __shared__ float xl[PREN];
  xl[tid] = bf2f(x1[(t * BB + b) * PREN + tid]);
  __syncthreads();
  int j = tid;
  float acc = 0.f;
#pragma unroll 4
  for (int k = 0; k < PREN; ++k) acc += xl[k] * W2[(size_t)k * PREN + j];
  acc = fmaxf(acc, 0.f);
  uint32_t idx = ((uint32_t)(t * BB + b)) * PREN + (uint32_t)j;
  acc = keep_mask(k0, k1, idx) ? acc * 2.f : 0.f;
  preTu[(size_t)t * 4096 + j * 16 + b] = f2bf(acc);
  if (t == 0) xpre0[j * 16 + b] = acc;
}

__global__ __launch_bounds__(256) void k_pm(const float *__restrict__ memory,
                                            const float *__restrict__ Wmem,
                                            u16 *__restrict__ pmu) {
  int p = blockIdx.x;          // 64 blocks
  int b = p & 15, jt = p >> 4;
  int tt = threadIdx.x;
  float acc[32];
#pragma unroll
  for (int j = 0; j < 32; ++j) acc[j] = 0.f;
  const float *mrow = memory + ((size_t)b * TENC + tt) * EDIM;
  const float *wb = Wmem + jt * 32;
  for (int e = 0; e < EDIM; ++e) {
    float mv = mrow[e];
    const float *wr = wb + (size_t)e * ATTN;
#pragma unroll
    for (int j = 0; j < 32; ++j) acc[j] += mv * wr[j];
  }
#pragma unroll
  for (int j = 0; j < 32; ++j)
    pmu[((size_t)(b * ATTN + jt * 32 + j)) * TENC + tt] = f2bf(acc[j]);
}

// ---------------- persistent cooperative decoder kernel ----------------
struct F2 { float x, y; };

union Scr {
  uint32_t xs1[112 * 16];                         // z1 x-stage, fp16 pairs [k2][16b]
  uint32_t xs2[160 * 16];                         // z2 x-stage
  struct { F2 part[16 * 64]; float hn[64]; } al;  // aLSTM reduce
  struct {
    float aw_l[96], awc_l[96];
    float lc[64 * 33];
    float pq[128];
    float ep[64 * 17];
  } att;                                          // attention energies (per 64-tt slab)
  struct { float e_l[256]; float red[32]; float smax, sinv; float part[32 * 33]; } ctc;
  struct { float xl[1536]; float part[12 * 81]; } out;
};

struct KArgs {
  const float *memory; const int *mlen;
  const float *aWih, *aWhh, *ab;
  const float *Wq, *vw, *convW, *ldW;
  const float *dWih, *dWhh, *db;
  const float *projW, *projB, *gateW, *gateB;
  const u16 *preTu, *pmu;
  float *aw, *awc, *ac, *dc, *xcat1, *xcat2, *z, *pqp, *ebuf;
  unsigned int *bar;
  float *mel, *gate, *algn;
};

// grid = 256 blocks (1/CU) x 1024 thr. LDS: w1h 57,344 + w2h 81,920 + Scr 14,080 = 153,344 B.
__global__ __launch_bounds__(NTHR) void k_persist(KArgs A) {
  __shared__ uint32_t w1h[112 * 128];   // z1 weight slice, fp16 k-pairs [k2][128cols]
  __shared__ uint32_t w2h[160 * 128];   // z2 weight slice
  __shared__ Scr s;
  const int cb = blockIdx.x;
  const int tid = threadIdx.x;
  const int q = cb >> 5;                // k-chunk 0..7  (z1: 224 rows, z2: 320 rows)
  const int c = cb & 31;                // col-block 0..31 (128 cols of 4096)

  // ---- one-time: stage fp16 weight slices into LDS (read HBM once, not 200x) ----
  for (int i = tid; i < 112 * 128; i += NTHR) {
    int k2 = i >> 7, col = i & 127, cg = c * 128 + col;
    int r0 = q * 224 + k2 * 2;
    float f0 = (r0 < 768) ? A.aWih[(size_t)r0 * 4096 + cg]
                          : A.aWhh[(size_t)(r0 - 768) * 4096 + cg];
    float f1 = (r0 + 1 < 768) ? A.aWih[(size_t)(r0 + 1) * 4096 + cg]
                              : A.aWhh[(size_t)(r0 - 767) * 4096 + cg];
    w1h[i] = packh2(f0, f1);
  }
  for (int i = tid; i < 160 * 128; i += NTHR) {
    int k2 = i >> 7, col = i & 127, cg = c * 128 + col;
    int r0 = q * 320 + k2 * 2;
    float f0 = (r0 < 1536) ? A.dWih[(size_t)r0 * 4096 + cg]
                           : A.dWhh[(size_t)(r0 - 1536) * 4096 + cg];
    float f1 = (r0 + 1 < 1536) ? A.dWih[(size_t)(r0 + 1) * 4096 + cg]
                               : A.dWhh[(size_t)(r0 - 1535) * 4096 + cg];
    w2h[i] = packh2(f0, f1);
  }
  __syncthreads();

  unsigned int ep = 0;
  for (int t = 0; t < TDEC; ++t) {
    // ================= phase Z1: z1 partials (all 256 blocks) =================
    for (int i = tid; i < 112 * 16; i += NTHR) {
      int k2 = i >> 4, b = i & 15;
      const float *xr = A.xcat1 + (size_t)(q * 224 + k2 * 2) * 16 + b;
      s.xs1[i] = packh2(xr[0], xr[16]);
    }
    __syncthreads();
    {
      int col = tid & 127, bg = tid >> 7;         // 128 cols x 8 groups of 2 batches
      float a0 = 0.f, a1 = 0.f;
      const uint32_t *wp = w1h + col;
      const uint32_t *xp = s.xs1 + bg * 2;
#pragma unroll 8
      for (int k2 = 0; k2 < 112; ++k2) {
        h2f16 w = u2h2(wp[k2 * 128]);
        a0 = fdot2(w, u2h2(xp[k2 * 16]), a0);
        a1 = fdot2(w, u2h2(xp[k2 * 16 + 1]), a1);
      }
      int cg = c * 128 + col;
      A.z[((size_t)q * 16 + bg * 2    ) * 4096 + cg] = a0;
      A.z[((size_t)q * 16 + bg * 2 + 1) * 4096 + cg] = a1;
    }
    gsync(A.bar, ++ep, cb);

    // ================= phase A-LSTM + pq partials (all 256 blocks) =================
    {
      int b = cb & 15, ug = cb >> 4;              // 16 batches x 16 u-groups of 64
      {
        int u_l = tid & 63, j = tid >> 6;         // j: kc(8) x gate-half(2)
        int kc = j & 7, gh = j >> 3;
        const float *zb = A.z + ((size_t)(kc * 16 + b)) * 4096 + gh * 2048 + (ug * 64 + u_l);
        F2 p; p.x = zb[0]; p.y = zb[1024];
        s.al.part[j * 64 + u_l] = p;
      }
      __syncthreads();
      if (tid < 64) {
        int uu = ug * 64 + tid;
        float g0 = 0.f, g1 = 0.f, g2 = 0.f, g3 = 0.f;
#pragma unroll
        for (int kc = 0; kc < 8; ++kc) {
          F2 v0 = s.al.part[kc * 64 + tid];
          F2 v1 = s.al.part[(8 + kc) * 64 + tid];
          g0 += v0.x; g1 += v0.y; g2 += v1.x; g3 += v1.y;
        }
        float zi = g0 + A.ab[uu], zf = g1 + A.ab[1024 + uu];
        float zg = g2 + A.ab[2048 + uu], zo = g3 + A.ab[3072 + uu];
        float cn = sigm(zf) * A.ac[b * 1024 + uu] + sigm(zi) * ftanh(zg);
        float hn = sigm(zo) * ftanh(cn);
        A.ac[b * 1024 + uu] = cn;
        A.xcat1[(size_t)(768 + uu) * 16 + b] = hn;
        A.xcat2[(size_t)uu * 16 + b] = hn;
        s.al.hn[tid] = hn;
      }
      __syncthreads();
      if (tid < 128) {
        float a = 0.f;
        const float *wq = A.Wq + (size_t)(ug * 64) * 128 + tid;
#pragma unroll 4
        for (int k = 0; k < 64; ++k) a += s.al.hn[k] * wq[(size_t)k * 128];
        A.pqp[(size_t)(b * 16 + ug) * 128 + tid] = a;
      }
    }
    gsync(A.bar, ++ep, cb);

    // ================= phase ATT-A: conv + energies (64 blocks: 16b x 4 tt-slabs) ====
    if (cb < 64) {
      int b = cb & 15, tq = cb >> 4;
      if (tid < 96) {
        int gi = tq * 64 - 16 + tid;
        bool ok = (gi >= 0 && gi < 256);
        s.att.aw_l[tid]  = ok ? A.aw[b * 256 + gi]  : 0.f;
        s.att.awc_l[tid] = ok ? A.awc[b * 256 + gi] : 0.f;
      }
      if (tid >= 128 && tid < 256) {
        int j = tid - 128;
        float sum = 0.f;
#pragma unroll
        for (int g = 0; g < 16; ++g) sum += A.pqp[(size_t)(b * 16 + g) * 128 + j];
        s.att.pq[j] = sum;
      }
      __syncthreads();
      {  // conv: 64 tt x 16 groups of 2 filters
        int tt_l = tid & 63, fg = tid >> 6;
        int f0 = fg * 2;
        float a0 = 0.f, a1 = 0.f;
        for (int k = 0; k < KSIZE; ++k) {
          float av = s.att.aw_l[tt_l + k + 1];
          float cv = s.att.awc_l[tt_l + k + 1];
          a0 += av * A.convW[f0 * 62 + k]       + cv * A.convW[f0 * 62 + 31 + k];
          a1 += av * A.convW[(f0 + 1) * 62 + k] + cv * A.convW[(f0 + 1) * 62 + 31 + k];
        }
        s.att.lc[tt_l * 33 + f0]     = a0;
        s.att.lc[tt_l * 33 + f0 + 1] = a1;
      }
      __syncthreads();
      {  // energies: 64 tt x 16 groups of 8 j
        int tt_l = tid & 63, g = tid >> 6;
        int tt = tq * 64 + tt_l, j0 = g * 8;
        float acc[8] = {0, 0, 0, 0, 0, 0, 0, 0};
        for (int f = 0; f < NFILT; ++f) {
          float lv = s.att.lc[tt_l * 33 + f];
          const float *lw = A.ldW + f * ATTN + j0;
#pragma unroll
          for (int jj = 0; jj < 8; ++jj) acc[jj] += lv * lw[jj];
        }
        float es = 0.f;
#pragma unroll
        for (int jj = 0; jj < 8; ++jj) {
          float sv = acc[jj] + s.att.pq[j0 + jj]
                   + bf2f(A.pmu[((size_t)(b * 128 + j0 + jj)) * 256 + tt]);
          es += ftanh(sv) * A.vw[j0 + jj];
        }
        s.att.ep[tt_l * 17 + g] = es;
      }
      __syncthreads();
      if (tid < 64) {
        float e = 0.f;
#pragma unroll
        for (int g = 0; g < 16; ++g) e += s.att.ep[tid * 17 + g];
        int tt = tq * 64 + tid;
        if (tt >= A.mlen[b]) e = -1e9f;
        A.ebuf[b * 256 + tt] = e;
      }
    }
    gsync(A.bar, ++ep, cb);

    // ===== phase ATT-C: softmax (replicated) + ctx (256 blocks: 16b x 16 e-chunks) ====
    {
      int b = cb & 15, ec = cb >> 4;
      if (tid < 256) s.ctc.e_l[tid] = A.ebuf[b * 256 + tid];
      __syncthreads();
      if (tid < 32) {
        float m = -1e30f;
#pragma unroll
        for (int i = 0; i < 8; ++i) m = fmaxf(m, s.ctc.e_l[tid * 8 + i]);
        s.ctc.red[tid] = m;
      }
      __syncthreads();
      if (tid == 0) {
        float m = -1e30f;
        for (int i = 0; i < 32; ++i) m = fmaxf(m, s.ctc.red[i]);
        s.ctc.smax = m;
      }
      __syncthreads();
      if (tid < 256) s.ctc.e_l[tid] = __expf(s.ctc.e_l[tid] - s.ctc.smax);
      __syncthreads();
      if (tid < 32) {
        float sm = 0.f;
#pragma unroll
        for (int i = 0; i < 8; ++i) sm += s.ctc.e_l[tid * 8 + i];
        s.ctc.red[tid] = sm;
      }
      __syncthreads();
      if (tid == 0) {
        float sm = 0.f;
        for (int i = 0; i < 32; ++i) sm += s.ctc.red[i];
        s.ctc.sinv = 1.f / sm;
      }
      __syncthreads();
      if (tid < 256) s.ctc.e_l[tid] *= s.ctc.sinv;    // e_l is now w
      __syncthreads();
      if (ec == 0 && tid < 256) {                     // one chunk-block owns state writes
        float w = s.ctc.e_l[tid];
        A.aw[b * 256 + tid] = w;
        A.awc[b * 256 + tid] += w;
        A.algn[((size_t)b * TDEC + t) * TENC + tid] = w;
      }
      {
        int e_l = tid & 31, sub = tid >> 5;           // 32 e x 32 tt-subsets of 8
        const float *mp = A.memory + ((size_t)(b * 256) + sub * 8) * 512 + ec * 32 + e_l;
        float a = 0.f;
#pragma unroll
        for (int i = 0; i < 8; ++i) a += s.ctc.e_l[sub * 8 + i] * mp[(size_t)i * 512];
        s.ctc.part[e_l * 33 + sub] = a;
      }
      __syncthreads();
      if (tid < 32) {
        float sum = 0.f;
#pragma unroll
        for (int i = 0; i < 32; ++i) sum += s.ctc.part[tid * 33 + i];
        int eg = ec * 32 + tid;
        A.xcat1[(size_t)(256 + eg) * 16 + b] = sum;
        A.xcat2[(size_t)(1024 + eg) * 16 + b] = sum;
      }
    }
    gsync(A.bar, ++ep, cb);

    // ================= phase Z2: z2 partials (all 256 blocks) =================
    for (int i = tid; i < 160 * 16; i += NTHR) {
      int k2 = i >> 4, b = i & 15;
      const float *xr = A.xcat2 + (size_t)(q * 320 + k2 * 2) * 16 + b;
      s.xs2[i] = packh2(xr[0], xr[16]);
    }
    __syncthreads();
    {
      int col = tid & 127, bg = tid >> 7;
      float a0 = 0.f, a1 = 0.f;
      const uint32_t *wp = w2h + col;
      const uint32_t *xp = s.xs2 + bg * 2;
#pragma unroll 8
      for (int k2 = 0; k2 < 160; ++k2) {
        h2f16 w = u2h2(wp[k2 * 128]);
        a0 = fdot2(w, u2h2(xp[k2 * 16]), a0);
        a1 = fdot2(w, u2h2(xp[k2 * 16 + 1]), a1);
      }
      int cg = c * 128 + col;
      A.z[((size_t)q * 16 + bg * 2    ) * 4096 + cg] = a0;
      A.z[((size_t)q * 16 + bg * 2 + 1) * 4096 + cg] = a1;
    }
    gsync(A.bar, ++ep, cb);

    // ============ phase OUT: dLSTM + projection (16 blocks) + pre prefetch (4) =======
    if (cb < 16) {
      int b = cb;
      {
        int u = tid;
        float zi = 0.f, zf = 0.f, zg = 0.f, zo = 0.f;
        for (int kc = 0; kc < 8; ++kc) {
          const float *zb = A.z + ((size_t)(kc * 16 + b)) * 4096;
          zi += zb[u]; zf += zb[u + 1024]; zg += zb[u + 2048]; zo += zb[u + 3072];
        }
        zi += A.db[u]; zf += A.db[u + 1024]; zg += A.db[u + 2048]; zo += A.db[u + 3072];
        float cn = sigm(zf) * A.dc[b * 1024 + u] + sigm(zi) * ftanh(zg);
        float hn = sigm(zo) * ftanh(cn);
        A.dc[b * 1024 + u] = cn;
        A.xcat2[(size_t)(1536 + u) * 16 + b] = hn;
        s.out.xl[u] = hn;
      }
      if (tid < 512) s.out.xl[1024 + tid] = A.xcat2[(size_t)(1024 + tid) * 16 + b];
      __syncthreads();
      if (tid < 960) {
        int col = tid % 80, kc = tid / 80;          // 12 k-groups x 128
        const float *wp = A.projW + (size_t)(kc * 128) * 80 + col;
        const float *xk = s.out.xl + kc * 128;
        float a = 0.f;
#pragma unroll 4
        for (int kk = 0; kk < 128; ++kk) a += xk[kk] * wp[(size_t)kk * 80];
        s.out.part[kc * 81 + col] = a;
      } else if (tid < 972) {
        int kc = tid - 960;
        const float *xk = s.out.xl + kc * 128;
        const float *gk = A.gateW + kc * 128;
        float a = 0.f;
#pragma unroll 4
        for (int kk = 0; kk < 128; ++kk) a += xk[kk] * gk[kk];
        s.out.part[kc * 81 + 80] = a;
      }
      __syncthreads();
      if (tid < 81) {
        float sum = 0.f;
#pragma unroll
        for (int kc = 0; kc < 12; ++kc) sum += s.out.part[kc * 81 + tid];
        if (tid < 80) A.mel[((size_t)b * 80 + tid) * TDEC + t] = sum + A.projB[tid];
        else          A.gate[(size_t)b * TDEC + t] = sum + A.gateB[0];
      }
    } else if (cb < 20) {
      if (t + 1 < TDEC) {
        int idx = (cb - 16) * 1024 + tid;
        A.xcat1[idx] = bf2f(A.preTu[(size_t)(t + 1) * 4096 + idx]);
      }
    }
    gsync(A.bar, ++ep, cb);
  }
}

extern "C" void kernel_launch(void *const *d_in, const int *in_sizes, int n_in,
                              void *d_out, int out_size, void *d_ws, size_t ws_size,
                              hipStream_t stream) {
  (void)in_sizes; (void)n_in; (void)out_size; (void)ws_size;
  const float *memory = (const float *)d_in[0];
  const float *dec_in = (const float *)d_in[1];
  const int   *mlen   = (const int *)d_in[2];
  const float *pw1    = (const float *)d_in[3];
  const float *pw2    = (const float *)d_in[4];
  const float *aWih   = (const float *)d_in[5];
  const float *aWhh   = (const float *)d_in[6];
  const float *ab     = (const float *)d_in[7];
  const float *wq     = (const float *)d_in[8];
  const float *wmem   = (const float *)d_in[9];
  const float *vw     = (const float *)d_in[10];
  const float *convW  = (const float *)d_in[11];
  const float *ldW    = (const float *)d_in[12];
  const float *dWih   = (const float *)d_in[13];
  const float *dWhh   = (const float *)d_in[14];
  const float *db     = (const float *)d_in[15];
  const float *projW  = (const float *)d_in[16];
  const float *projB  = (const float *)d_in[17];
  const float *gateW  = (const float *)d_in[18];
  const float *gateB  = (const float *)d_in[19];

  float *out_mel  = (float *)d_out;
  float *out_gate = out_mel + (size_t)16 * 80 * 200;
  float *out_algn = out_gate + (size_t)16 * 200;

  float *ws = (float *)d_ws;
  float *aw    = ws + OFF_AW;
  float *awc   = ws + OFF_AWC;
  float *ac    = ws + OFF_AC;
  float *dc    = ws + OFF_DC;
  float *xcat1 = ws + OFF_XCAT1;
  float *xcat2 = ws + OFF_XCAT2;
  float *xpre  = xcat1;
  u16 *preTu = (u16 *)(ws + OFF_PRETU);
  u16 *pmu   = (u16 *)(ws + OFF_PMU);
  float *z    = ws + OFF_Z;
  float *pqp  = ws + OFF_PQP;
  float *ebuf = ws + OFF_EBUF;
  unsigned int *bar = (unsigned int *)(ws + OFF_BAR);
  u16 *x1u   = (u16 *)z;                   // prenet temp alias (pre-loop only)

  hipMemsetAsync(ws, 0, STATE_F * sizeof(float), stream);
  hipMemsetAsync(bar, 0, 2048 * sizeof(unsigned int), stream);

  uint32_t K1a, K1b, K2a, K2b;
  tf2x32(0u, 42u, 0u, 0u, K1a, K1b);
  tf2x32(0u, 42u, 0u, 1u, K2a, K2b);

  k_prenet1<<<TDEC * BB, 256, 0, stream>>>(dec_in, pw1, x1u, K1a, K1b);
  k_prenet2<<<TDEC * BB, 256, 0, stream>>>(x1u, pw2, preTu, xpre, K2a, K2b);
  k_pm<<<64, 256, 0, stream>>>(memory, wmem, pmu);

  KArgs ka;
  ka.memory = memory; ka.mlen = mlen;
  ka.aWih = aWih; ka.aWhh = aWhh; ka.ab = ab;
  ka.Wq = wq; ka.vw = vw; ka.convW = convW; ka.ldW = ldW;
  ka.dWih = dWih; ka.dWhh = dWhh; ka.db = db;
  ka.projW = projW; ka.projB = projB; ka.gateW = gateW; ka.gateB = gateB;
  ka.preTu = preTu; ka.pmu = pmu;
  ka.aw = aw; ka.awc = awc; ka.ac = ac; ka.dc = dc;
  ka.xcat1 = xcat1; ka.xcat2 = xcat2; ka.z = z; ka.pqp = pqp; ka.ebuf = ebuf;
  ka.bar = bar;
  ka.mel = out_mel; ka.gate = out_gate; ka.algn = out_algn;

  void *kp[] = { &ka };
  hipLaunchCooperativeKernel((void *)k_persist, dim3(NBLK), dim3(NTHR), kp, 0, stream);
}

// Round 3
// 27276.114 us; speedup vs baseline: 4.1115x; 1.2437x over previous
//
#include <hip/hip_runtime.h>
#include <stdint.h>

typedef unsigned short u16;
typedef _Float16 h2f16 __attribute__((ext_vector_type(2)));

#define BB    16
#define TENC  256
#define TDEC  200
#define NMELS 80
#define EDIM  512
#define PREN  256
#define ARN   1024
#define ATTN  128
#define NFILT 32
#define KSIZE 31

#define NBLK  256
#define NTHR  1024

// ---- ws layout (floats); max used offset ~1,353,728 f = 5.41 MB (< proven 7.44 MB) ----
#define OFF_AW     0          // 4096
#define OFF_AWC    4096       // 4096
#define OFF_AC     8192       // 16384
#define OFF_DC     24576      // 16384
#define OFF_XCAT1  49152      // [pre(256)|ctx(512)|ah(1024)] rows x16b = 28672 f
#define OFF_XCAT2  77824      // [ah(1024)|ctx(512)|dh(1024)] rows x16b = 40960 f
#define STATE_F    118784
#define OFF_PRETU  118784     // u16[819200]  pre bf16 [t][j*16+b]
#define OFF_PMU    528384     // u16[524288]  pm bf16 [b][j][tt]
#define OFF_Z      790528     // f32 8*16*4096 = 524288  split-K partials (z1 then z2)
#define OFF_PQP    1314816    // f32 16*16*128 = 32768   pq partials [b][ug][j]
#define OFF_EBUF   1347584    // f32 16*256 = 4096       pre-softmax energies
#define OFF_BAR    1351680    // uint[2048] hierarchical barrier (8KB)

__host__ __device__ inline void tf2x32(uint32_t k0, uint32_t k1, uint32_t x0, uint32_t x1,
                                       uint32_t &y0, uint32_t &y1) {
  uint32_t ks2 = k0 ^ k1 ^ 0x1BD11BDAu;
  x0 += k0; x1 += k1;
  const int R0[4] = {13, 15, 26, 6};
  const int R1[4] = {17, 29, 16, 24};
#pragma unroll
  for (int g = 0; g < 5; ++g) {
    const int *R = (g & 1) ? R1 : R0;
#pragma unroll
    for (int i = 0; i < 4; ++i) {
      x0 += x1;
      x1 = (x1 << R[i]) | (x1 >> (32 - R[i]));
      x1 ^= x0;
    }
    switch (g) {
      case 0: x0 += k1;  x1 += ks2 + 1u; break;
      case 1: x0 += ks2; x1 += k0 + 2u;  break;
      case 2: x0 += k0;  x1 += k1 + 3u;  break;
      case 3: x0 += k1;  x1 += ks2 + 4u; break;
      case 4: x0 += ks2; x1 += k0 + 5u;  break;
    }
  }
  y0 = x0; y1 = x1;
}

__device__ inline bool keep_mask(uint32_t k0, uint32_t k1, uint32_t idx) {
  uint32_t y0, y1;
  tf2x32(k0, k1, 0u, idx, y0, y1);
  return (((y0 ^ y1) >> 31) == 0u);
}

__device__ inline float bf2f(u16 v) {
  union { uint32_t u; float f; } x;
  x.u = ((uint32_t)v) << 16;
  return x.f;
}
__device__ inline u16 f2bf(float f) {
  union { float f; uint32_t u; } x;
  x.f = f;
  uint32_t r = ((x.u >> 16) & 1u) + 0x7FFFu;
  return (u16)((x.u + r) >> 16);
}
__device__ inline float sigm(float x) { return 1.f / (1.f + __expf(-x)); }
__device__ inline float ftanh(float x) {
  x = fminf(fmaxf(x, -15.f), 15.f);
  float e = __expf(2.f * x);
  return (e - 1.f) / (e + 1.f);
}

__device__ inline uint32_t packh2(float a, float b) {
  h2f16 h; h[0] = (_Float16)a; h[1] = (_Float16)b;
  union { h2f16 h; uint32_t u; } x; x.h = h; return x.u;
}
__device__ inline h2f16 u2h2(uint32_t u) {
  union { uint32_t u; h2f16 h; } x; x.u = u; return x.h;
}
__device__ inline float fdot2(h2f16 a, h2f16 b, float c) {
#if __has_builtin(__builtin_amdgcn_fdot2)
  return __builtin_amdgcn_fdot2(a, b, c, false);
#else
  return (float)a[0] * (float)b[0] + (float)a[1] * (float)b[1] + c;
#endif
}

// ---- coherent (LLC-direct, sc0 sc1) scalar access for cross-block data --------
// Relaxed system-scope atomics bypass L1/L2 (no stale lines) and emit ZERO cache
// maintenance (no buffer_wbl2 / buffer_inv). LLC is the coherence point.
__device__ inline float cload(const float *p) {
  uint32_t u = __hip_atomic_load((uint32_t *)p, __ATOMIC_RELAXED,
                                 __HIP_MEMORY_SCOPE_SYSTEM);
  union { uint32_t u; float f; } x; x.u = u; return x.f;
}
__device__ inline void cstore(float *p, float v) {
  union { float f; uint32_t u; } x; x.f = v;
  __hip_atomic_store((uint32_t *)p, x.u, __ATOMIC_RELAXED,
                     __HIP_MEMORY_SCOPE_SYSTEM);
}

// ---- fence-free hierarchical epoch barrier ------------------------------------
// __syncthreads() drains each wave's vmcnt before s_barrier, so every coherent
// store of the block is complete at the LLC before tid0 arrives. All counter
// ops are relaxed system-scope (sc0 sc1) -> no cache maintenance anywhere.
__device__ inline void gsync(unsigned int *bar, unsigned int e, int cb) {
  __syncthreads();
  if (threadIdx.x == 0) {
    asm volatile("s_waitcnt vmcnt(0)" ::: "memory");
    int g = cb & 7;
    unsigned int *arr = bar + g * 64;
    unsigned int *gct = bar + 512;
    unsigned int *rel = bar + 576 + g * 64;
    unsigned int old = __hip_atomic_fetch_add(arr, 1u, __ATOMIC_RELAXED,
                                              __HIP_MEMORY_SCOPE_SYSTEM);
    if (old == e * 32u - 1u) {                 // last arriver of this group
      unsigned int o2 = __hip_atomic_fetch_add(gct, 1u, __ATOMIC_RELAXED,
                                               __HIP_MEMORY_SCOPE_SYSTEM);
      if (o2 == e * 8u - 1u) {                 // last group globally -> publish
#pragma unroll
        for (int g2 = 0; g2 < 8; ++g2)
          __hip_atomic_store(bar + 576 + g2 * 64, e, __ATOMIC_RELAXED,
                             __HIP_MEMORY_SCOPE_SYSTEM);
      }
    }
    while (__hip_atomic_load(rel, __ATOMIC_RELAXED, __HIP_MEMORY_SCOPE_SYSTEM) < e)
      __builtin_amdgcn_s_sleep(1);
  }
  __syncthreads();
}

// ---------------- setup kernels (one-time, unchanged semantics) ----------------
__global__ __launch_bounds__(256) void k_prenet1(const float *__restrict__ dec_in,
                                                 const float *__restrict__ W1,
                                                 u16 *__restrict__ x1,
                                                 uint32_t k0, uint32_t k1) {
  int bid = blockIdx.x;
  int t = bid >> 4, b = bid & 15;
  int tid = threadIdx.x;
  __shared__ float di[NMELS];
  if (tid < NMELS)
    di[tid] = (t == 0) ? 0.f : dec_in[((size_t)b * NMELS + tid) * TDEC + (t - 1)];
  __syncthreads();
  int j = tid;
  float acc = 0.f;
#pragma unroll 4
  for (int m = 0; m < NMELS; ++m) acc += di[m] * W1[(size_t)m * PREN + j];
  acc = fmaxf(acc, 0.f);
  uint32_t idx = ((uint32_t)(t * BB + b)) * PREN + (uint32_t)j;
  acc = keep_mask(k0, k1, idx) ? acc * 2.f : 0.f;
  x1[(t * BB + b) * PREN + j] = f2bf(acc);
}

__global__ __launch_bounds__(256) void k_prenet2(const u16 *__restrict__ x1,
                                                 const float *__restrict__ W2,
                                                 u16 *__restrict__ preTu,
                                                 float *__restrict__ xpre0,
                                                 uint32_t k0, uint32_t k1) {
  int bid = blockIdx.x;
  int t = bid >> 4, b = bid & 15;
  int tid = threadIdx.x;
  __shared__ float xl[PREN];
  xl[tid] = bf2f(x1[(t * BB + b) * PREN + tid]);
  __syncthreads();
  int j = tid;
  float acc = 0.f;
#pragma unroll 4
  for (int k = 0; k < PREN; ++k) acc += xl[k] * W2[(size_t)k * PREN + j];
  acc = fmaxf(acc, 0.f);
  uint32_t idx = ((uint32_t)(t * BB + b)) * PREN + (uint32_t)j;
  acc = keep_mask(k0, k1, idx) ? acc * 2.f : 0.f;
  preTu[(size_t)t * 4096 + j * 16 + b] = f2bf(acc);
  if (t == 0) xpre0[j * 16 + b] = acc;
}

__global__ __launch_bounds__(256) void k_pm(const float *__restrict__ memory,
                                            const float *__restrict__ Wmem,
                                            u16 *__restrict__ pmu) {
  int p = blockIdx.x;          // 64 blocks
  int b = p & 15, jt = p >> 4;
  int tt = threadIdx.x;
  float acc[32];
#pragma unroll
  for (int j = 0; j < 32; ++j) acc[j] = 0.f;
  const float *mrow = memory + ((size_t)b * TENC + tt) * EDIM;
  const float *wb = Wmem + jt * 32;
  for (int e = 0; e < EDIM; ++e) {
    float mv = mrow[e];
    const float *wr = wb + (size_t)e * ATTN;
#pragma unroll
    for (int j = 0; j < 32; ++j) acc[j] += mv * wr[j];
  }
#pragma unroll
  for (int j = 0; j < 32; ++j)
    pmu[((size_t)(b * ATTN + jt * 32 + j)) * TENC + tt] = f2bf(acc[j]);
}

// ---------------- persistent cooperative decoder kernel ----------------
struct F2 { float x, y; };

union Scr {
  uint32_t xs1[112 * 16];                         // z1 x-stage, fp16 pairs [k2][16b]
  uint32_t xs2[160 * 16];                         // z2 x-stage
  struct { F2 part[16 * 64]; float hn[64]; } al;  // aLSTM reduce
  struct {
    float aw_l[96], awc_l[96];
    float lc[64 * 33];
    float pq[128];
    float ep[64 * 17];
  } att;                                          // attention energies (per 64-tt slab)
  struct { float e_l[256]; float red[32]; float smax, sinv; float part[32 * 33]; } ctc;
  struct { float xl[1536]; float part[12 * 81]; } out;
};

struct KArgs {
  const float *memory; const int *mlen;
  const float *aWih, *aWhh, *ab;
  const float *Wq, *vw, *convW, *ldW;
  const float *dWih, *dWhh, *db;
  const float *projW, *projB, *gateW, *gateB;
  const u16 *preTu, *pmu;
  float *aw, *awc, *ac, *dc, *xcat1, *xcat2, *z, *pqp, *ebuf;
  unsigned int *bar;
  float *mel, *gate, *algn;
};

// grid = 256 blocks (1/CU) x 1024 thr. LDS: w1h 57,344 + w2h 81,920 + Scr 14,080 = 153,344 B.
__global__ __launch_bounds__(NTHR) void k_persist(KArgs A) {
  __shared__ uint32_t w1h[112 * 128];   // z1 weight slice, fp16 k-pairs [k2][128cols]
  __shared__ uint32_t w2h[160 * 128];   // z2 weight slice
  __shared__ Scr s;
  const int cb = blockIdx.x;
  const int tid = threadIdx.x;
  const int q = cb >> 5;                // k-chunk 0..7  (z1: 224 rows, z2: 320 rows)
  const int c = cb & 31;                // col-block 0..31 (128 cols of 4096)

  // ---- one-time: stage fp16 weight slices into LDS (read HBM once, not 200x) ----
  for (int i = tid; i < 112 * 128; i += NTHR) {
    int k2 = i >> 7, col = i & 127, cg = c * 128 + col;
    int r0 = q * 224 + k2 * 2;
    float f0 = (r0 < 768) ? A.aWih[(size_t)r0 * 4096 + cg]
                          : A.aWhh[(size_t)(r0 - 768) * 4096 + cg];
    float f1 = (r0 + 1 < 768) ? A.aWih[(size_t)(r0 + 1) * 4096 + cg]
                              : A.aWhh[(size_t)(r0 - 767) * 4096 + cg];
    w1h[i] = packh2(f0, f1);
  }
  for (int i = tid; i < 160 * 128; i += NTHR) {
    int k2 = i >> 7, col = i & 127, cg = c * 128 + col;
    int r0 = q * 320 + k2 * 2;
    float f0 = (r0 < 1536) ? A.dWih[(size_t)r0 * 4096 + cg]
                           : A.dWhh[(size_t)(r0 - 1536) * 4096 + cg];
    float f1 = (r0 + 1 < 1536) ? A.dWih[(size_t)(r0 + 1) * 4096 + cg]
                               : A.dWhh[(size_t)(r0 - 1535) * 4096 + cg];
    w2h[i] = packh2(f0, f1);
  }
  __syncthreads();

  unsigned int ep = 0;
  for (int t = 0; t < TDEC; ++t) {
    // ================= phase Z1: z1 partials (all 256 blocks) =================
    for (int i = tid; i < 112 * 16; i += NTHR) {
      int k2 = i >> 4, b = i & 15;
      const float *xr = A.xcat1 + (size_t)(q * 224 + k2 * 2) * 16 + b;
      s.xs1[i] = packh2(cload(xr), cload(xr + 16));
    }
    __syncthreads();
    {
      int col = tid & 127, bg = tid >> 7;         // 128 cols x 8 groups of 2 batches
      float a0 = 0.f, a1 = 0.f;
      const uint32_t *wp = w1h + col;
      const uint32_t *xp = s.xs1 + bg * 2;
#pragma unroll 8
      for (int k2 = 0; k2 < 112; ++k2) {
        h2f16 w = u2h2(wp[k2 * 128]);
        a0 = fdot2(w, u2h2(xp[k2 * 16]), a0);
        a1 = fdot2(w, u2h2(xp[k2 * 16 + 1]), a1);
      }
      int cg = c * 128 + col;
      cstore(&A.z[((size_t)q * 16 + bg * 2    ) * 4096 + cg], a0);
      cstore(&A.z[((size_t)q * 16 + bg * 2 + 1) * 4096 + cg], a1);
    }
    gsync(A.bar, ++ep, cb);

    // ================= phase A-LSTM + pq partials (all 256 blocks) =================
    {
      int b = cb & 15, ug = cb >> 4;              // 16 batches x 16 u-groups of 64
      {
        int u_l = tid & 63, j = tid >> 6;         // j: kc(8) x gate-half(2)
        int kc = j & 7, gh = j >> 3;
        const float *zb = A.z + ((size_t)(kc * 16 + b)) * 4096 + gh * 2048 + (ug * 64 + u_l);
        F2 p; p.x = cload(zb); p.y = cload(zb + 1024);
        s.al.part[j * 64 + u_l] = p;
      }
      __syncthreads();
      if (tid < 64) {
        int uu = ug * 64 + tid;
        float g0 = 0.f, g1 = 0.f, g2 = 0.f, g3 = 0.f;
#pragma unroll
        for (int kc = 0; kc < 8; ++kc) {
          F2 v0 = s.al.part[kc * 64 + tid];
          F2 v1 = s.al.part[(8 + kc) * 64 + tid];
          g0 += v0.x; g1 += v0.y; g2 += v1.x; g3 += v1.y;
        }
        float zi = g0 + A.ab[uu], zf = g1 + A.ab[1024 + uu];
        float zg = g2 + A.ab[2048 + uu], zo = g3 + A.ab[3072 + uu];
        float cn = sigm(zf) * A.ac[b * 1024 + uu] + sigm(zi) * ftanh(zg);
        float hn = sigm(zo) * ftanh(cn);
        A.ac[b * 1024 + uu] = cn;
        cstore(&A.xcat1[(size_t)(768 + uu) * 16 + b], hn);
        cstore(&A.xcat2[(size_t)uu * 16 + b], hn);
        s.al.hn[tid] = hn;
      }
      __syncthreads();
      if (tid < 128) {
        float a = 0.f;
        const float *wq = A.Wq + (size_t)(ug * 64) * 128 + tid;
#pragma unroll 4
        for (int k = 0; k < 64; ++k) a += s.al.hn[k] * wq[(size_t)k * 128];
        cstore(&A.pqp[(size_t)(b * 16 + ug) * 128 + tid], a);
      }
    }
    gsync(A.bar, ++ep, cb);

    // ================= phase ATT-A: conv + energies (64 blocks: 16b x 4 tt-slabs) ====
    if (cb < 64) {
      int b = cb & 15, tq = cb >> 4;
      if (tid < 96) {
        int gi = tq * 64 - 16 + tid;
        bool ok = (gi >= 0 && gi < 256);
        s.att.aw_l[tid]  = ok ? cload(&A.aw[b * 256 + gi])  : 0.f;
        s.att.awc_l[tid] = ok ? cload(&A.awc[b * 256 + gi]) : 0.f;
      }
      if (tid >= 128 && tid < 256) {
        int j = tid - 128;
        float sum = 0.f;
#pragma unroll
        for (int g = 0; g < 16; ++g) sum += cload(&A.pqp[(size_t)(b * 16 + g) * 128 + j]);
        s.att.pq[j] = sum;
      }
      __syncthreads();
      {  // conv: 64 tt x 16 groups of 2 filters
        int tt_l = tid & 63, fg = tid >> 6;
        int f0 = fg * 2;
        float a0 = 0.f, a1 = 0.f;
        for (int k = 0; k < KSIZE; ++k) {
          float av = s.att.aw_l[tt_l + k + 1];
          float cv = s.att.awc_l[tt_l + k + 1];
          a0 += av * A.convW[f0 * 62 + k]       + cv * A.convW[f0 * 62 + 31 + k];
          a1 += av * A.convW[(f0 + 1) * 62 + k] + cv * A.convW[(f0 + 1) * 62 + 31 + k];
        }
        s.att.lc[tt_l * 33 + f0]     = a0;
        s.att.lc[tt_l * 33 + f0 + 1] = a1;
      }
      __syncthreads();
      {  // energies: 64 tt x 16 groups of 8 j
        int tt_l = tid & 63, g = tid >> 6;
        int tt = tq * 64 + tt_l, j0 = g * 8;
        float acc[8] = {0, 0, 0, 0, 0, 0, 0, 0};
        for (int f = 0; f < NFILT; ++f) {
          float lv = s.att.lc[tt_l * 33 + f];
          const float *lw = A.ldW + f * ATTN + j0;
#pragma unroll
          for (int jj = 0; jj < 8; ++jj) acc[jj] += lv * lw[jj];
        }
        float es = 0.f;
#pragma unroll
        for (int jj = 0; jj < 8; ++jj) {
          float sv = acc[jj] + s.att.pq[j0 + jj]
                   + bf2f(A.pmu[((size_t)(b * 128 + j0 + jj)) * 256 + tt]);
          es += ftanh(sv) * A.vw[j0 + jj];
        }
        s.att.ep[tt_l * 17 + g] = es;
      }
      __syncthreads();
      if (tid < 64) {
        float e = 0.f;
#pragma unroll
        for (int g = 0; g < 16; ++g) e += s.att.ep[tid * 17 + g];
        int tt = tq * 64 + tid;
        if (tt >= A.mlen[b]) e = -1e9f;
        cstore(&A.ebuf[b * 256 + tt], e);
      }
    }
    gsync(A.bar, ++ep, cb);

    // ===== phase ATT-C: softmax (replicated) + ctx (256 blocks: 16b x 16 e-chunks) ====
    {
      int b = cb & 15, ec = cb >> 4;
      if (tid < 256) s.ctc.e_l[tid] = cload(&A.ebuf[b * 256 + tid]);
      __syncthreads();
      if (tid < 32) {
        float m = -1e30f;
#pragma unroll
        for (int i = 0; i < 8; ++i) m = fmaxf(m, s.ctc.e_l[tid * 8 + i]);
        s.ctc.red[tid] = m;
      }
      __syncthreads();
      if (tid == 0) {
        float m = -1e30f;
        for (int i = 0; i < 32; ++i) m = fmaxf(m, s.ctc.red[i]);
        s.ctc.smax = m;
      }
      __syncthreads();
      if (tid < 256) s.ctc.e_l[tid] = __expf(s.ctc.e_l[tid] - s.ctc.smax);
      __syncthreads();
      if (tid < 32) {
        float sm = 0.f;
#pragma unroll
        for (int i = 0; i < 8; ++i) sm += s.ctc.e_l[tid * 8 + i];
        s.ctc.red[tid] = sm;
      }
      __syncthreads();
      if (tid == 0) {
        float sm = 0.f;
        for (int i = 0; i < 32; ++i) sm += s.ctc.red[i];
        s.ctc.sinv = 1.f / sm;
      }
      __syncthreads();
      if (tid < 256) s.ctc.e_l[tid] *= s.ctc.sinv;    // e_l is now w
      __syncthreads();
      if (ec == 0 && tid < 256) {                     // one chunk-block owns state writes
        float w = s.ctc.e_l[tid];
        cstore(&A.aw[b * 256 + tid], w);
        cstore(&A.awc[b * 256 + tid], cload(&A.awc[b * 256 + tid]) + w);
        A.algn[((size_t)b * TDEC + t) * TENC + tid] = w;
      }
      {
        int e_l = tid & 31, sub = tid >> 5;           // 32 e x 32 tt-subsets of 8
        const float *mp = A.memory + ((size_t)(b * 256) + sub * 8) * 512 + ec * 32 + e_l;
        float a = 0.f;
#pragma unroll
        for (int i = 0; i < 8; ++i) a += s.ctc.e_l[sub * 8 + i] * mp[(size_t)i * 512];
        s.ctc.part[e_l * 33 + sub] = a;
      }
      __syncthreads();
      if (tid < 32) {
        float sum = 0.f;
#pragma unroll
        for (int i = 0; i < 32; ++i) sum += s.ctc.part[tid * 33 + i];
        int eg = ec * 32 + tid;
        cstore(&A.xcat1[(size_t)(256 + eg) * 16 + b], sum);
        cstore(&A.xcat2[(size_t)(1024 + eg) * 16 + b], sum);
      }
    }
    gsync(A.bar, ++ep, cb);

    // ================= phase Z2: z2 partials (all 256 blocks) =================
    for (int i = tid; i < 160 * 16; i += NTHR) {
      int k2 = i >> 4, b = i & 15;
      const float *xr = A.xcat2 + (size_t)(q * 320 + k2 * 2) * 16 + b;
      s.xs2[i] = packh2(cload(xr), cload(xr + 16));
    }
    __syncthreads();
    {
      int col = tid & 127, bg = tid >> 7;
      float a0 = 0.f, a1 = 0.f;
      const uint32_t *wp = w2h + col;
      const uint32_t *xp = s.xs2 + bg * 2;
#pragma unroll 8
      for (int k2 = 0; k2 < 160; ++k2) {
        h2f16 w = u2h2(wp[k2 * 128]);
        a0 = fdot2(w, u2h2(xp[k2 * 16]), a0);
        a1 = fdot2(w, u2h2(xp[k2 * 16 + 1]), a1);
      }
      int cg = c * 128 + col;
      cstore(&A.z[((size_t)q * 16 + bg * 2    ) * 4096 + cg], a0);
      cstore(&A.z[((size_t)q * 16 + bg * 2 + 1) * 4096 + cg], a1);
    }
    gsync(A.bar, ++ep, cb);

    // ============ phase OUT: dLSTM + projection (16 blocks) + pre prefetch (4) =======
    if (cb < 16) {
      int b = cb;
      {
        int u = tid;
        float zi = 0.f, zf = 0.f, zg = 0.f, zo = 0.f;
        for (int kc = 0; kc < 8; ++kc) {
          const float *zb = A.z + ((size_t)(kc * 16 + b)) * 4096;
          zi += cload(zb + u); zf += cload(zb + u + 1024);
          zg += cload(zb + u + 2048); zo += cload(zb + u + 3072);
        }
        zi += A.db[u]; zf += A.db[u + 1024]; zg += A.db[u + 2048]; zo += A.db[u + 3072];
        float cn = sigm(zf) * A.dc[b * 1024 + u] + sigm(zi) * ftanh(zg);
        float hn = sigm(zo) * ftanh(cn);
        A.dc[b * 1024 + u] = cn;
        cstore(&A.xcat2[(size_t)(1536 + u) * 16 + b], hn);
        s.out.xl[u] = hn;
      }
      if (tid < 512) s.out.xl[1024 + tid] = cload(&A.xcat2[(size_t)(1024 + tid) * 16 + b]);
      __syncthreads();
      if (tid < 960) {
        int col = tid % 80, kc = tid / 80;          // 12 k-groups x 128
        const float *wp = A.projW + (size_t)(kc * 128) * 80 + col;
        const float *xk = s.out.xl + kc * 128;
        float a = 0.f;
#pragma unroll 4
        for (int kk = 0; kk < 128; ++kk) a += xk[kk] * wp[(size_t)kk * 80];
        s.out.part[kc * 81 + col] = a;
      } else if (tid < 972) {
        int kc = tid - 960;
        const float *xk = s.out.xl + kc * 128;
        const float *gk = A.gateW + kc * 128;
        float a = 0.f;
#pragma unroll 4
        for (int kk = 0; kk < 128; ++kk) a += xk[kk] * gk[kk];
        s.out.part[kc * 81 + 80] = a;
      }
      __syncthreads();
      if (tid < 81) {
        float sum = 0.f;
#pragma unroll
        for (int kc = 0; kc < 12; ++kc) sum += s.out.part[kc * 81 + tid];
        if (tid < 80) A.mel[((size_t)b * 80 + tid) * TDEC + t] = sum + A.projB[tid];
        else          A.gate[(size_t)b * TDEC + t] = sum + A.gateB[0];
      }
    } else if (cb < 20) {
      if (t + 1 < TDEC) {
        int idx = (cb - 16) * 1024 + tid;
        cstore(&A.xcat1[idx], bf2f(A.preTu[(size_t)(t + 1) * 4096 + idx]));
      }
    }
    gsync(A.bar, ++ep, cb);
  }
}

extern "C" void kernel_launch(void *const *d_in, const int *in_sizes, int n_in,
                              void *d_out, int out_size, void *d_ws, size_t ws_size,
                              hipStream_t stream) {
  (void)in_sizes; (void)n_in; (void)out_size; (void)ws_size;
  const float *memory = (const float *)d_in[0];
  const float *dec_in = (const float *)d_in[1];
  const int   *mlen   = (const int *)d_in[2];
  const float *pw1    = (const float *)d_in[3];
  const float *pw2    = (const float *)d_in[4];
  const float *aWih   = (const float *)d_in[5];
  const float *aWhh   = (const float *)d_in[6];
  const float *ab     = (const float *)d_in[7];
  const float *wq     = (const float *)d_in[8];
  const float *wmem   = (const float *)d_in[9];
  const float *vw     = (const float *)d_in[10];
  const float *convW  = (const float *)d_in[11];
  const float *ldW    = (const float *)d_in[12];
  const float *dWih   = (const float *)d_in[13];
  const float *dWhh   = (const float *)d_in[14];
  const float *db     = (const float *)d_in[15];
  const float *projW  = (const float *)d_in[16];
  const float *projB  = (const float *)d_in[17];
  const float *gateW  = (const float *)d_in[18];
  const float *gateB  = (const float *)d_in[19];

  float *out_mel  = (float *)d_out;
  float *out_gate = out_mel + (size_t)16 * 80 * 200;
  float *out_algn = out_gate + (size_t)16 * 200;

  float *ws = (float *)d_ws;
  float *aw    = ws + OFF_AW;
  float *awc   = ws + OFF_AWC;
  float *ac    = ws + OFF_AC;
  float *dc    = ws + OFF_DC;
  float *xcat1 = ws + OFF_XCAT1;
  float *xcat2 = ws + OFF_XCAT2;
  float *xpre  = xcat1;
  u16 *preTu = (u16 *)(ws + OFF_PRETU);
  u16 *pmu   = (u16 *)(ws + OFF_PMU);
  float *z    = ws + OFF_Z;
  float *pqp  = ws + OFF_PQP;
  float *ebuf = ws + OFF_EBUF;
  unsigned int *bar = (unsigned int *)(ws + OFF_BAR);
  u16 *x1u   = (u16 *)z;                   // prenet temp alias (pre-loop only)

  hipMemsetAsync(ws, 0, STATE_F * sizeof(float), stream);
  hipMemsetAsync(bar, 0, 2048 * sizeof(unsigned int), stream);

  uint32_t K1a, K1b, K2a, K2b;
  tf2x32(0u, 42u, 0u, 0u, K1a, K1b);
  tf2x32(0u, 42u, 0u, 1u, K2a, K2b);

  k_prenet1<<<TDEC * BB, 256, 0, stream>>>(dec_in, pw1, x1u, K1a, K1b);
  k_prenet2<<<TDEC * BB, 256, 0, stream>>>(x1u, pw2, preTu, xpre, K2a, K2b);
  k_pm<<<64, 256, 0, stream>>>(memory, wmem, pmu);

  KArgs ka;
  ka.memory = memory; ka.mlen = mlen;
  ka.aWih = aWih; ka.aWhh = aWhh; ka.ab = ab;
  ka.Wq = wq; ka.vw = vw; ka.convW = convW; ka.ldW = ldW;
  ka.dWih = dWih; ka.dWhh = dWhh; ka.db = db;
  ka.projW = projW; ka.projB = projB; ka.gateW = gateW; ka.gateB = gateB;
  ka.preTu = preTu; ka.pmu = pmu;
  ka.aw = aw; ka.awc = awc; ka.ac = ac; ka.dc = dc;
  ka.xcat1 = xcat1; ka.xcat2 = xcat2; ka.z = z; ka.pqp = pqp; ka.ebuf = ebuf;
  ka.bar = bar;
  ka.mel = out_mel; ka.gate = out_gate; ka.algn = out_algn;

  void *kp[] = { &ka };
  hipLaunchCooperativeKernel((void *)k_persist, dim3(NBLK), dim3(NTHR), kp, 0, stream);
}

// Round 4
// 27005.350 us; speedup vs baseline: 4.1527x; 1.0100x over previous
//
#include <hip/hip_runtime.h>
#include <stdint.h>

typedef unsigned short u16;
typedef _Float16 h2f16 __attribute__((ext_vector_type(2)));

#define BB    16
#define TENC  256
#define TDEC  200
#define NMELS 80
#define EDIM  512
#define PREN  256
#define ARN   1024
#define ATTN  128
#define NFILT 32
#define KSIZE 31

#define NBLK  256
#define NTHR  1024

// ---- ws layout (floats); max used offset ~1,353,728 f = 5.41 MB (< proven 7.44 MB) ----
#define OFF_AW     0          // 4096
#define OFF_AWC    4096       // 4096
#define OFF_AC     8192       // 16384
#define OFF_DC     24576      // 16384
#define OFF_XCAT1  49152      // [pre(256)|ctx(512)|ah(1024)] rows x16b = 28672 f
#define OFF_XCAT2  77824      // [ah(1024)|ctx(512)|dh(1024)] rows x16b = 40960 f
#define STATE_F    118784
#define OFF_PRETU  118784     // u16[819200]  pre bf16 [t][j*16+b]
#define OFF_PMU    528384     // u16[524288]  pm bf16 [b][j][tt]
#define OFF_Z      790528     // f32 8*16*4096 = 524288  split-K partials (z1 then z2)
#define OFF_PQP    1314816    // f32 16*16*128 = 32768   pq partials [b][ug][j]
#define OFF_EBUF   1347584    // f32 16*256 = 4096       pre-softmax energies
#define OFF_BAR    1351680    // uint[2048] hierarchical barrier (8KB)

__host__ __device__ inline void tf2x32(uint32_t k0, uint32_t k1, uint32_t x0, uint32_t x1,
                                       uint32_t &y0, uint32_t &y1) {
  uint32_t ks2 = k0 ^ k1 ^ 0x1BD11BDAu;
  x0 += k0; x1 += k1;
  const int R0[4] = {13, 15, 26, 6};
  const int R1[4] = {17, 29, 16, 24};
#pragma unroll
  for (int g = 0; g < 5; ++g) {
    const int *R = (g & 1) ? R1 : R0;
#pragma unroll
    for (int i = 0; i < 4; ++i) {
      x0 += x1;
      x1 = (x1 << R[i]) | (x1 >> (32 - R[i]));
      x1 ^= x0;
    }
    switch (g) {
      case 0: x0 += k1;  x1 += ks2 + 1u; break;
      case 1: x0 += ks2; x1 += k0 + 2u;  break;
      case 2: x0 += k0;  x1 += k1 + 3u;  break;
      case 3: x0 += k1;  x1 += ks2 + 4u; break;
      case 4: x0 += ks2; x1 += k0 + 5u;  break;
    }
  }
  y0 = x0; y1 = x1;
}

__device__ inline bool keep_mask(uint32_t k0, uint32_t k1, uint32_t idx) {
  uint32_t y0, y1;
  tf2x32(k0, k1, 0u, idx, y0, y1);
  return (((y0 ^ y1) >> 31) == 0u);
}

__device__ inline float bf2f(u16 v) {
  union { uint32_t u; float f; } x;
  x.u = ((uint32_t)v) << 16;
  return x.f;
}
__device__ inline u16 f2bf(float f) {
  union { float f; uint32_t u; } x;
  x.f = f;
  uint32_t r = ((x.u >> 16) & 1u) + 0x7FFFu;
  return (u16)((x.u + r) >> 16);
}
__device__ inline float sigm(float x) { return 1.f / (1.f + __expf(-x)); }
__device__ inline float ftanh(float x) {
  x = fminf(fmaxf(x, -15.f), 15.f);
  float e = __expf(2.f * x);
  return (e - 1.f) / (e + 1.f);
}

__device__ inline uint32_t packh2(float a, float b) {
  h2f16 h; h[0] = (_Float16)a; h[1] = (_Float16)b;
  union { h2f16 h; uint32_t u; } x; x.h = h; return x.u;
}
__device__ inline h2f16 u2h2(uint32_t u) {
  union { uint32_t u; h2f16 h; } x; x.u = u; return x.h;
}
__device__ inline float fdot2(h2f16 a, h2f16 b, float c) {
#if __has_builtin(__builtin_amdgcn_fdot2)
  return __builtin_amdgcn_fdot2(a, b, c, false);
#else
  return (float)a[0] * (float)b[0] + (float)a[1] * (float)b[1] + c;
#endif
}

// ---- coherent (LLC-resident) access for cross-block data: AGENT scope ----------
// Agent scope is the minimal cross-XCD-correct scope: relaxed agent atomics
// bypass the XCD-private L2 (coherence point = LLC) and emit ZERO cache
// maintenance. System scope (round 3) risks routing past the memory-side LLC
// to the DF/DRAM path -> ~2us per dependent trip; agent keeps it LLC-hit.
__device__ inline float cload(const float *p) {
  uint32_t u = __hip_atomic_load((uint32_t *)p, __ATOMIC_RELAXED,
                                 __HIP_MEMORY_SCOPE_AGENT);
  union { uint32_t u; float f; } x; x.u = u; return x.f;
}
__device__ inline void cstore(float *p, float v) {
  union { float f; uint32_t u; } x; x.f = v;
  __hip_atomic_store((uint32_t *)p, x.u, __ATOMIC_RELAXED,
                     __HIP_MEMORY_SCOPE_AGENT);
}
__device__ inline void cload8(const float *p, float &a, float &b) {
  unsigned long long u = __hip_atomic_load((const unsigned long long *)p,
                                           __ATOMIC_RELAXED,
                                           __HIP_MEMORY_SCOPE_AGENT);
  union { unsigned long long u; float f[2]; } x; x.u = u;
  a = x.f[0]; b = x.f[1];
}

// ---- fence-free hierarchical epoch barrier (agent scope, relaxed) --------------
__device__ inline void gsync(unsigned int *bar, unsigned int e, int cb) {
  __syncthreads();
  if (threadIdx.x == 0) {
    asm volatile("s_waitcnt vmcnt(0)" ::: "memory");
    int g = cb & 7;
    unsigned int *arr = bar + g * 64;
    unsigned int *gct = bar + 512;
    unsigned int *rel = bar + 576 + g * 64;
    unsigned int old = __hip_atomic_fetch_add(arr, 1u, __ATOMIC_RELAXED,
                                              __HIP_MEMORY_SCOPE_AGENT);
    if (old == e * 32u - 1u) {                 // last arriver of this group
      unsigned int o2 = __hip_atomic_fetch_add(gct, 1u, __ATOMIC_RELAXED,
                                               __HIP_MEMORY_SCOPE_AGENT);
      if (o2 == e * 8u - 1u) {                 // last group globally -> publish
#pragma unroll
        for (int g2 = 0; g2 < 8; ++g2)
          __hip_atomic_store(bar + 576 + g2 * 64, e, __ATOMIC_RELAXED,
                             __HIP_MEMORY_SCOPE_AGENT);
      }
    }
    while (__hip_atomic_load(rel, __ATOMIC_RELAXED, __HIP_MEMORY_SCOPE_AGENT) < e)
      __builtin_amdgcn_s_sleep(1);
  }
  __syncthreads();
}

// ---------------- setup kernels (one-time, unchanged semantics) ----------------
__global__ __launch_bounds__(256) void k_prenet1(const float *__restrict__ dec_in,
                                                 const float *__restrict__ W1,
                                                 u16 *__restrict__ x1,
                                                 uint32_t k0, uint32_t k1) {
  int bid = blockIdx.x;
  int t = bid >> 4, b = bid & 15;
  int tid = threadIdx.x;
  __shared__ float di[NMELS];
  if (tid < NMELS)
    di[tid] = (t == 0) ? 0.f : dec_in[((size_t)b * NMELS + tid) * TDEC + (t - 1)];
  __syncthreads();
  int j = tid;
  float acc = 0.f;
#pragma unroll 4
  for (int m = 0; m < NMELS; ++m) acc += di[m] * W1[(size_t)m * PREN + j];
  acc = fmaxf(acc, 0.f);
  uint32_t idx = ((uint32_t)(t * BB + b)) * PREN + (uint32_t)j;
  acc = keep_mask(k0, k1, idx) ? acc * 2.f : 0.f;
  x1[(t * BB + b) * PREN + j] = f2bf(acc);
}

__global__ __launch_bounds__(256) void k_prenet2(const u16 *__restrict__ x1,
                                                 const float *__restrict__ W2,
                                                 u16 *__restrict__ preTu,
                                                 float *__restrict__ xpre0,
                                                 uint32_t k0, uint32_t k1) {
  int bid = blockIdx.x;
  int t = bid >> 4, b = bid & 15;
  int tid = threadIdx.x;
  __shared__ float xl[PREN];
  xl[tid] = bf2f(x1[(t * BB + b) * PREN + tid]);
  __syncthreads();
  int j = tid;
  float acc = 0.f;
#pragma unroll 4
  for (int k = 0; k < PREN; ++k) acc += xl[k] * W2[(size_t)k * PREN + j];
  acc = fmaxf(acc, 0.f);
  uint32_t idx = ((uint32_t)(t * BB + b)) * PREN + (uint32_t)j;
  acc = keep_mask(k0, k1, idx) ? acc * 2.f : 0.f;
  preTu[(size_t)t * 4096 + j * 16 + b] = f2bf(acc);
  if (t == 0) xpre0[j * 16 + b] = acc;
}

__global__ __launch_bounds__(256) void k_pm(const float *__restrict__ memory,
                                            const float *__restrict__ Wmem,
                                            u16 *__restrict__ pmu) {
  int p = blockIdx.x;          // 64 blocks
  int b = p & 15, jt = p >> 4;
  int tt = threadIdx.x;
  float acc[32];
#pragma unroll
  for (int j = 0; j < 32; ++j) acc[j] = 0.f;
  const float *mrow = memory + ((size_t)b * TENC + tt) * EDIM;
  const float *wb = Wmem + jt * 32;
  for (int e = 0; e < EDIM; ++e) {
    float mv = mrow[e];
    const float *wr = wb + (size_t)e * ATTN;
#pragma unroll
    for (int j = 0; j < 32; ++j) acc[j] += mv * wr[j];
  }
#pragma unroll
  for (int j = 0; j < 32; ++j)
    pmu[((size_t)(b * ATTN + jt * 32 + j)) * TENC + tt] = f2bf(acc[j]);
}

// ---------------- persistent cooperative decoder kernel ----------------
struct F2 { float x, y; };

union Scr {
  uint32_t xs1[112 * 16];                         // z1 x-stage, fp16 pairs [k2][16b]
  uint32_t xs2[160 * 16];                         // z2 x-stage
  struct { F2 part[16 * 64]; float hn[64]; } al;  // aLSTM reduce
  struct {
    float aw_l[96], awc_l[96];
    float lc[64 * 33];
    float pq[128];
    float ep[64 * 17];
  } att;                                          // attention energies (per 64-tt slab)
  struct { float e_l[256]; float red[32]; float smax, sinv; float part[32 * 33]; } ctc;
  struct { float xl[1536]; float part[12 * 81]; } out;
};

struct KArgs {
  const float *memory; const int *mlen;
  const float *aWih, *aWhh, *ab;
  const float *Wq, *vw, *convW, *ldW;
  const float *dWih, *dWhh, *db;
  const float *projW, *projB, *gateW, *gateB;
  const u16 *preTu, *pmu;
  float *aw, *awc, *ac, *dc, *xcat1, *xcat2, *z, *pqp, *ebuf;
  unsigned int *bar;
  float *mel, *gate, *algn;
};

// grid = 256 blocks (1/CU) x 1024 thr. LDS: w1h 57,344 + w2h 81,920 + Scr 14,080 = 153,344 B.
__global__ __launch_bounds__(NTHR) void k_persist(KArgs A) {
  __shared__ uint32_t w1h[112 * 128];   // z1 weight slice, fp16 k-pairs [k2][128cols]
  __shared__ uint32_t w2h[160 * 128];   // z2 weight slice
  __shared__ Scr s;
  const int cb = blockIdx.x;
  const int tid = threadIdx.x;
  const int q = cb >> 5;                // k-chunk 0..7  (z1: 224 rows, z2: 320 rows)
  const int c = cb & 31;                // col-block 0..31 (128 cols of 4096)

  // ---- one-time: stage fp16 weight slices into LDS (read HBM once, not 200x) ----
  for (int i = tid; i < 112 * 128; i += NTHR) {
    int k2 = i >> 7, col = i & 127, cg = c * 128 + col;
    int r0 = q * 224 + k2 * 2;
    float f0 = (r0 < 768) ? A.aWih[(size_t)r0 * 4096 + cg]
                          : A.aWhh[(size_t)(r0 - 768) * 4096 + cg];
    float f1 = (r0 + 1 < 768) ? A.aWih[(size_t)(r0 + 1) * 4096 + cg]
                              : A.aWhh[(size_t)(r0 - 767) * 4096 + cg];
    w1h[i] = packh2(f0, f1);
  }
  for (int i = tid; i < 160 * 128; i += NTHR) {
    int k2 = i >> 7, col = i & 127, cg = c * 128 + col;
    int r0 = q * 320 + k2 * 2;
    float f0 = (r0 < 1536) ? A.dWih[(size_t)r0 * 4096 + cg]
                           : A.dWhh[(size_t)(r0 - 1536) * 4096 + cg];
    float f1 = (r0 + 1 < 1536) ? A.dWih[(size_t)(r0 + 1) * 4096 + cg]
                               : A.dWhh[(size_t)(r0 - 1535) * 4096 + cg];
    w2h[i] = packh2(f0, f1);
  }
  __syncthreads();

  unsigned int ep = 0;
  for (int t = 0; t < TDEC; ++t) {
    // ================= phase Z1: z1 partials (all 256 blocks) =================
    // 8B coherent loads: pairs (b2,b2+1) of rows (r, r+1) -> 2 packed LDS entries.
    for (int i = tid; i < 112 * 8; i += NTHR) {
      int k2 = i >> 3, b2 = (i & 7) * 2;
      const float *xr = A.xcat1 + (size_t)(q * 224 + k2 * 2) * 16 + b2;
      float r0a, r0b, r1a, r1b;
      cload8(xr, r0a, r0b);
      cload8(xr + 16, r1a, r1b);
      s.xs1[k2 * 16 + b2]     = packh2(r0a, r1a);
      s.xs1[k2 * 16 + b2 + 1] = packh2(r0b, r1b);
    }
    __syncthreads();
    {
      int col = tid & 127, bg = tid >> 7;         // 128 cols x 8 groups of 2 batches
      float a0 = 0.f, a1 = 0.f;
      const uint32_t *wp = w1h + col;
      const uint32_t *xp = s.xs1 + bg * 2;
#pragma unroll 8
      for (int k2 = 0; k2 < 112; ++k2) {
        h2f16 w = u2h2(wp[k2 * 128]);
        a0 = fdot2(w, u2h2(xp[k2 * 16]), a0);
        a1 = fdot2(w, u2h2(xp[k2 * 16 + 1]), a1);
      }
      int cg = c * 128 + col;
      cstore(&A.z[((size_t)q * 16 + bg * 2    ) * 4096 + cg], a0);
      cstore(&A.z[((size_t)q * 16 + bg * 2 + 1) * 4096 + cg], a1);
    }
    gsync(A.bar, ++ep, cb);

    // ================= phase A-LSTM + pq partials (all 256 blocks) =================
    {
      int b = cb & 15, ug = cb >> 4;              // 16 batches x 16 u-groups of 64
      {
        int u_l = tid & 63, j = tid >> 6;         // j: kc(8) x gate-half(2)
        int kc = j & 7, gh = j >> 3;
        const float *zb = A.z + ((size_t)(kc * 16 + b)) * 4096 + gh * 2048 + (ug * 64 + u_l);
        F2 p; p.x = cload(zb); p.y = cload(zb + 1024);
        s.al.part[j * 64 + u_l] = p;
      }
      __syncthreads();
      if (tid < 64) {
        int uu = ug * 64 + tid;
        float g0 = 0.f, g1 = 0.f, g2 = 0.f, g3 = 0.f;
#pragma unroll
        for (int kc = 0; kc < 8; ++kc) {
          F2 v0 = s.al.part[kc * 64 + tid];
          F2 v1 = s.al.part[(8 + kc) * 64 + tid];
          g0 += v0.x; g1 += v0.y; g2 += v1.x; g3 += v1.y;
        }
        float zi = g0 + A.ab[uu], zf = g1 + A.ab[1024 + uu];
        float zg = g2 + A.ab[2048 + uu], zo = g3 + A.ab[3072 + uu];
        float cn = sigm(zf) * A.ac[b * 1024 + uu] + sigm(zi) * ftanh(zg);
        float hn = sigm(zo) * ftanh(cn);
        A.ac[b * 1024 + uu] = cn;
        cstore(&A.xcat1[(size_t)(768 + uu) * 16 + b], hn);
        cstore(&A.xcat2[(size_t)uu * 16 + b], hn);
        s.al.hn[tid] = hn;
      }
      __syncthreads();
      if (tid < 128) {
        float a = 0.f;
        const float *wq = A.Wq + (size_t)(ug * 64) * 128 + tid;
#pragma unroll 4
        for (int k = 0; k < 64; ++k) a += s.al.hn[k] * wq[(size_t)k * 128];
        cstore(&A.pqp[(size_t)(b * 16 + ug) * 128 + tid], a);
      }
    }
    gsync(A.bar, ++ep, cb);

    // ================= phase ATT-A: conv + energies (64 blocks: 16b x 4 tt-slabs) ====
    if (cb < 64) {
      int b = cb & 15, tq = cb >> 4;
      if (tid < 96) {
        int gi = tq * 64 - 16 + tid;
        bool ok = (gi >= 0 && gi < 256);
        s.att.aw_l[tid]  = ok ? cload(&A.aw[b * 256 + gi])  : 0.f;
        s.att.awc_l[tid] = ok ? cload(&A.awc[b * 256 + gi]) : 0.f;
      }
      if (tid >= 128 && tid < 256) {
        int j = tid - 128;
        float sum = 0.f;
#pragma unroll
        for (int g = 0; g < 16; ++g) sum += cload(&A.pqp[(size_t)(b * 16 + g) * 128 + j]);
        s.att.pq[j] = sum;
      }
      __syncthreads();
      {  // conv: 64 tt x 16 groups of 2 filters
        int tt_l = tid & 63, fg = tid >> 6;
        int f0 = fg * 2;
        float a0 = 0.f, a1 = 0.f;
        for (int k = 0; k < KSIZE; ++k) {
          float av = s.att.aw_l[tt_l + k + 1];
          float cv = s.att.awc_l[tt_l + k + 1];
          a0 += av * A.convW[f0 * 62 + k]       + cv * A.convW[f0 * 62 + 31 + k];
          a1 += av * A.convW[(f0 + 1) * 62 + k] + cv * A.convW[(f0 + 1) * 62 + 31 + k];
        }
        s.att.lc[tt_l * 33 + f0]     = a0;
        s.att.lc[tt_l * 33 + f0 + 1] = a1;
      }
      __syncthreads();
      {  // energies: 64 tt x 16 groups of 8 j
        int tt_l = tid & 63, g = tid >> 6;
        int tt = tq * 64 + tt_l, j0 = g * 8;
        float acc[8] = {0, 0, 0, 0, 0, 0, 0, 0};
        for (int f = 0; f < NFILT; ++f) {
          float lv = s.att.lc[tt_l * 33 + f];
          const float *lw = A.ldW + f * ATTN + j0;
#pragma unroll
          for (int jj = 0; jj < 8; ++jj) acc[jj] += lv * lw[jj];
        }
        float es = 0.f;
#pragma unroll
        for (int jj = 0; jj < 8; ++jj) {
          float sv = acc[jj] + s.att.pq[j0 + jj]
                   + bf2f(A.pmu[((size_t)(b * 128 + j0 + jj)) * 256 + tt]);
          es += ftanh(sv) * A.vw[j0 + jj];
        }
        s.att.ep[tt_l * 17 + g] = es;
      }
      __syncthreads();
      if (tid < 64) {
        float e = 0.f;
#pragma unroll
        for (int g = 0; g < 16; ++g) e += s.att.ep[tid * 17 + g];
        int tt = tq * 64 + tid;
        if (tt >= A.mlen[b]) e = -1e9f;
        cstore(&A.ebuf[b * 256 + tt], e);
      }
    }
    gsync(A.bar, ++ep, cb);

    // ===== phase ATT-C: softmax (replicated) + ctx (256 blocks: 16b x 16 e-chunks) ====
    {
      int b = cb & 15, ec = cb >> 4;
      if (tid < 256) s.ctc.e_l[tid] = cload(&A.ebuf[b * 256 + tid]);
      __syncthreads();
      if (tid < 32) {
        float m = -1e30f;
#pragma unroll
        for (int i = 0; i < 8; ++i) m = fmaxf(m, s.ctc.e_l[tid * 8 + i]);
        s.ctc.red[tid] = m;
      }
      __syncthreads();
      if (tid == 0) {
        float m = -1e30f;
        for (int i = 0; i < 32; ++i) m = fmaxf(m, s.ctc.red[i]);
        s.ctc.smax = m;
      }
      __syncthreads();
      if (tid < 256) s.ctc.e_l[tid] = __expf(s.ctc.e_l[tid] - s.ctc.smax);
      __syncthreads();
      if (tid < 32) {
        float sm = 0.f;
#pragma unroll
        for (int i = 0; i < 8; ++i) sm += s.ctc.e_l[tid * 8 + i];
        s.ctc.red[tid] = sm;
      }
      __syncthreads();
      if (tid == 0) {
        float sm = 0.f;
        for (int i = 0; i < 32; ++i) sm += s.ctc.red[i];
        s.ctc.sinv = 1.f / sm;
      }
      __syncthreads();
      if (tid < 256) s.ctc.e_l[tid] *= s.ctc.sinv;    // e_l is now w
      __syncthreads();
      if (ec == 0 && tid < 256) {                     // one chunk-block owns state writes
        float w = s.ctc.e_l[tid];
        cstore(&A.aw[b * 256 + tid], w);
        cstore(&A.awc[b * 256 + tid], cload(&A.awc[b * 256 + tid]) + w);
        A.algn[((size_t)b * TDEC + t) * TENC + tid] = w;
      }
      {
        int e_l = tid & 31, sub = tid >> 5;           // 32 e x 32 tt-subsets of 8
        const float *mp = A.memory + ((size_t)(b * 256) + sub * 8) * 512 + ec * 32 + e_l;
        float a = 0.f;
#pragma unroll
        for (int i = 0; i < 8; ++i) a += s.ctc.e_l[sub * 8 + i] * mp[(size_t)i * 512];
        s.ctc.part[e_l * 33 + sub] = a;
      }
      __syncthreads();
      if (tid < 32) {
        float sum = 0.f;
#pragma unroll
        for (int i = 0; i < 32; ++i) sum += s.ctc.part[tid * 33 + i];
        int eg = ec * 32 + tid;
        cstore(&A.xcat1[(size_t)(256 + eg) * 16 + b], sum);
        cstore(&A.xcat2[(size_t)(1024 + eg) * 16 + b], sum);
      }
    }
    gsync(A.bar, ++ep, cb);

    // ================= phase Z2: z2 partials (all 256 blocks) =================
    for (int i = tid; i < 160 * 8; i += NTHR) {
      int k2 = i >> 3, b2 = (i & 7) * 2;
      const float *xr = A.xcat2 + (size_t)(q * 320 + k2 * 2) * 16 + b2;
      float r0a, r0b, r1a, r1b;
      cload8(xr, r0a, r0b);
      cload8(xr + 16, r1a, r1b);
      s.xs2[k2 * 16 + b2]     = packh2(r0a, r1a);
      s.xs2[k2 * 16 + b2 + 1] = packh2(r0b, r1b);
    }
    __syncthreads();
    {
      int col = tid & 127, bg = tid >> 7;
      float a0 = 0.f, a1 = 0.f;
      const uint32_t *wp = w2h + col;
      const uint32_t *xp = s.xs2 + bg * 2;
#pragma unroll 8
      for (int k2 = 0; k2 < 160; ++k2) {
        h2f16 w = u2h2(wp[k2 * 128]);
        a0 = fdot2(w, u2h2(xp[k2 * 16]), a0);
        a1 = fdot2(w, u2h2(xp[k2 * 16 + 1]), a1);
      }
      int cg = c * 128 + col;
      cstore(&A.z[((size_t)q * 16 + bg * 2    ) * 4096 + cg], a0);
      cstore(&A.z[((size_t)q * 16 + bg * 2 + 1) * 4096 + cg], a1);
    }
    gsync(A.bar, ++ep, cb);

    // ============ phase OUT: dLSTM + projection (16 blocks) + pre prefetch (4) =======
    if (cb < 16) {
      int b = cb;
      {
        int u = tid;
        float zi = 0.f, zf = 0.f, zg = 0.f, zo = 0.f;
        for (int kc = 0; kc < 8; ++kc) {
          const float *zb = A.z + ((size_t)(kc * 16 + b)) * 4096;
          zi += cload(zb + u); zf += cload(zb + u + 1024);
          zg += cload(zb + u + 2048); zo += cload(zb + u + 3072);
        }
        zi += A.db[u]; zf += A.db[u + 1024]; zg += A.db[u + 2048]; zo += A.db[u + 3072];
        float cn = sigm(zf) * A.dc[b * 1024 + u] + sigm(zi) * ftanh(zg);
        float hn = sigm(zo) * ftanh(cn);
        A.dc[b * 1024 + u] = cn;
        cstore(&A.xcat2[(size_t)(1536 + u) * 16 + b], hn);
        s.out.xl[u] = hn;
      }
      if (tid < 512) s.out.xl[1024 + tid] = cload(&A.xcat2[(size_t)(1024 + tid) * 16 + b]);
      __syncthreads();
      if (tid < 960) {
        int col = tid % 80, kc = tid / 80;          // 12 k-groups x 128
        const float *wp = A.projW + (size_t)(kc * 128) * 80 + col;
        const float *xk = s.out.xl + kc * 128;
        float a = 0.f;
#pragma unroll 4
        for (int kk = 0; kk < 128; ++kk) a += xk[kk] * wp[(size_t)kk * 80];
        s.out.part[kc * 81 + col] = a;
      } else if (tid < 972) {
        int kc = tid - 960;
        const float *xk = s.out.xl + kc * 128;
        const float *gk = A.gateW + kc * 128;
        float a = 0.f;
#pragma unroll 4
        for (int kk = 0; kk < 128; ++kk) a += xk[kk] * gk[kk];
        s.out.part[kc * 81 + 80] = a;
      }
      __syncthreads();
      if (tid < 81) {
        float sum = 0.f;
#pragma unroll
        for (int kc = 0; kc < 12; ++kc) sum += s.out.part[kc * 81 + tid];
        if (tid < 80) A.mel[((size_t)b * 80 + tid) * TDEC + t] = sum + A.projB[tid];
        else          A.gate[(size_t)b * TDEC + t] = sum + A.gateB[0];
      }
    } else if (cb < 20) {
      if (t + 1 < TDEC) {
        int idx = (cb - 16) * 1024 + tid;
        cstore(&A.xcat1[idx], bf2f(A.preTu[(size_t)(t + 1) * 4096 + idx]));
      }
    }
    gsync(A.bar, ++ep, cb);
  }
}

extern "C" void kernel_launch(void *const *d_in, const int *in_sizes, int n_in,
                              void *d_out, int out_size, void *d_ws, size_t ws_size,
                              hipStream_t stream) {
  (void)in_sizes; (void)n_in; (void)out_size; (void)ws_size;
  const float *memory = (const float *)d_in[0];
  const float *dec_in = (const float *)d_in[1];
  const int   *mlen   = (const int *)d_in[2];
  const float *pw1    = (const float *)d_in[3];
  const float *pw2    = (const float *)d_in[4];
  const float *aWih   = (const float *)d_in[5];
  const float *aWhh   = (const float *)d_in[6];
  const float *ab     = (const float *)d_in[7];
  const float *wq     = (const float *)d_in[8];
  const float *wmem   = (const float *)d_in[9];
  const float *vw     = (const float *)d_in[10];
  const float *convW  = (const float *)d_in[11];
  const float *ldW    = (const float *)d_in[12];
  const float *dWih   = (const float *)d_in[13];
  const float *dWhh   = (const float *)d_in[14];
  const float *db     = (const float *)d_in[15];
  const float *projW  = (const float *)d_in[16];
  const float *projB  = (const float *)d_in[17];
  const float *gateW  = (const float *)d_in[18];
  const float *gateB  = (const float *)d_in[19];

  float *out_mel  = (float *)d_out;
  float *out_gate = out_mel + (size_t)16 * 80 * 200;
  float *out_algn = out_gate + (size_t)16 * 200;

  float *ws = (float *)d_ws;
  float *aw    = ws + OFF_AW;
  float *awc   = ws + OFF_AWC;
  float *ac    = ws + OFF_AC;
  float *dc    = ws + OFF_DC;
  float *xcat1 = ws + OFF_XCAT1;
  float *xcat2 = ws + OFF_XCAT2;
  float *xpre  = xcat1;
  u16 *preTu = (u16 *)(ws + OFF_PRETU);
  u16 *pmu   = (u16 *)(ws + OFF_PMU);
  float *z    = ws + OFF_Z;
  float *pqp  = ws + OFF_PQP;
  float *ebuf = ws + OFF_EBUF;
  unsigned int *bar = (unsigned int *)(ws + OFF_BAR);
  u16 *x1u   = (u16 *)z;                   // prenet temp alias (pre-loop only)

  hipMemsetAsync(ws, 0, STATE_F * sizeof(float), stream);
  hipMemsetAsync(bar, 0, 2048 * sizeof(unsigned int), stream);

  uint32_t K1a, K1b, K2a, K2b;
  tf2x32(0u, 42u, 0u, 0u, K1a, K1b);
  tf2x32(0u, 42u, 0u, 1u, K2a, K2b);

  k_prenet1<<<TDEC * BB, 256, 0, stream>>>(dec_in, pw1, x1u, K1a, K1b);
  k_prenet2<<<TDEC * BB, 256, 0, stream>>>(x1u, pw2, preTu, xpre, K2a, K2b);
  k_pm<<<64, 256, 0, stream>>>(memory, wmem, pmu);

  KArgs ka;
  ka.memory = memory; ka.mlen = mlen;
  ka.aWih = aWih; ka.aWhh = aWhh; ka.ab = ab;
  ka.Wq = wq; ka.vw = vw; ka.convW = convW; ka.ldW = ldW;
  ka.dWih = dWih; ka.dWhh = dWhh; ka.db = db;
  ka.projW = projW; ka.projB = projB; ka.gateW = gateW; ka.gateB = gateB;
  ka.preTu = preTu; ka.pmu = pmu;
  ka.aw = aw; ka.awc = awc; ka.ac = ac; ka.dc = dc;
  ka.xcat1 = xcat1; ka.xcat2 = xcat2; ka.z = z; ka.pqp = pqp; ka.ebuf = ebuf;
  ka.bar = bar;
  ka.mel = out_mel; ka.gate = out_gate; ka.algn = out_algn;

  void *kp[] = { &ka };
  hipLaunchCooperativeKernel((void *)k_persist, dim3(NBLK), dim3(NTHR), kp, 0, stream);
}